// Round 10
// baseline (294.003 us; speedup 1.0000x reference)
//
#include <hip/hip_runtime.h>
#include <math.h>

typedef unsigned short u16;
typedef __bf16 bf16x8 __attribute__((ext_vector_type(8)));
typedef float f32x4 __attribute__((ext_vector_type(4)));

__device__ __forceinline__ u16 f2bf(float f){
  union{float f; unsigned u;} v; v.f = f;
  return (u16)((v.u + 0x7fffu + ((v.u >> 16) & 1u)) >> 16);
}
__device__ __forceinline__ float bf2f(u16 b){
  union{unsigned u; float f;} v; v.u = (unsigned)b << 16; return v.f;
}

#define LOG2E 1.4426950408889634f

// ---------------------------------------------------------------------------
__global__ void tpose_cast(u16* __restrict__ dst, const float* __restrict__ src,
                           int R, int C, float scale){
  __shared__ float t[32][33];
  int c0 = blockIdx.x * 32, r0 = blockIdx.y * 32;
  int tx = threadIdx.x, ty = threadIdx.y;
  #pragma unroll
  for (int i = 0; i < 4; i++)
    t[ty + i*8][tx] = src[(size_t)(r0 + ty + i*8) * C + c0 + tx];
  __syncthreads();
  #pragma unroll
  for (int i = 0; i < 4; i++)
    dst[(size_t)(c0 + ty + i*8) * R + r0 + tx] = f2bf(t[tx][ty + i*8] * scale);
}

// biasPb[b][q][kt][l15][fk] = bf16( (sp+ed)[b][q][kt*128 + fk*16 + l15] * log2e )
__global__ void bias_prep(u16* __restrict__ dst, const float* __restrict__ sp,
                          const float* __restrict__ ed){
  int t = blockIdx.x * blockDim.x + threadIdx.x;   // 16*512*128
  int row = t >> 7, c0 = (t & 127) * 4;
  size_t base = (size_t)row * 512;
  float4 s = *(const float4*)&sp[base + c0];
  float4 e = *(const float4*)&ed[base + c0];
  int kt = c0 >> 7, cw = c0 & 127, fk = cw >> 4, l0 = cw & 15;
  u16* o = dst + base + kt*128 + fk;
  o[(l0+0)*8] = f2bf((s.x+e.x)*LOG2E);
  o[(l0+1)*8] = f2bf((s.y+e.y)*LOG2E);
  o[(l0+2)*8] = f2bf((s.z+e.z)*LOG2E);
  o[(l0+3)*8] = f2bf((s.w+e.w)*LOG2E);
}

__global__ void build_qkvb(float* __restrict__ qkvb, const float* __restrict__ bv){
  int i = blockIdx.x * blockDim.x + threadIdx.x;
  if (i < 2304) qkvb[i] = (i < 1536) ? 0.f : bv[i - 1536];
}

// ---------------------------------------------------------------------------
__global__ __launch_bounds__(256) void ln_kernel(
    const float* __restrict__ x,
    const float* __restrict__ g1, const float* __restrict__ be1,
    const float* __restrict__ g2, const float* __restrict__ be2,
    u16* __restrict__ h1, u16* __restrict__ h2){
  const int lane = threadIdx.x & 63, wave = threadIdx.x >> 6;
  const int row = blockIdx.x * 4 + wave;
  const float4* xr = (const float4*)(x + (size_t)row * 768);
  float4 v[3];
  float sum = 0.f, sq = 0.f;
  #pragma unroll
  for (int c = 0; c < 3; c++){
    v[c] = xr[lane + 64*c];
    sum += v[c].x + v[c].y + v[c].z + v[c].w;
    sq  += v[c].x*v[c].x + v[c].y*v[c].y + v[c].z*v[c].z + v[c].w*v[c].w;
  }
  #pragma unroll
  for (int d = 1; d < 64; d <<= 1){ sum += __shfl_xor(sum, d); sq += __shfl_xor(sq, d); }
  float mu  = sum * (1.f/768.f);
  float var = sq * (1.f/768.f) - mu*mu;
  float rs  = rsqrtf(var + 1e-5f);
  #pragma unroll
  for (int c = 0; c < 3; c++){
    int f4 = lane + 64*c;
    float4 ga = ((const float4*)g1)[f4], ba = ((const float4*)be1)[f4];
    float4 gb = ((const float4*)g2)[f4], bb = ((const float4*)be2)[f4];
    float nx = (v[c].x-mu)*rs, ny = (v[c].y-mu)*rs, nz = (v[c].z-mu)*rs, nw = (v[c].w-mu)*rs;
    ushort4 o1{f2bf(nx*ga.x+ba.x), f2bf(ny*ga.y+ba.y), f2bf(nz*ga.z+ba.z), f2bf(nw*ga.w+ba.w)};
    ushort4 o2{f2bf(nx*gb.x+bb.x), f2bf(ny*gb.y+bb.y), f2bf(nz*gb.z+bb.z), f2bf(nw*gb.w+bb.w)};
    ((ushort4*)(h1 + (size_t)row*768))[f4] = o1;
    ((ushort4*)(h2 + (size_t)row*768))[f4] = o2;
  }
}

// ---------------------------------------------------------------------------
// GEMM (128x128 tile, 64x64/wave), proven R4 structure. For N=768 outputs.
// EPI 3: +bias+resid(f32) -> bf16   EPI 4: +bias+resid(bf16) -> f32
template<int EPI>
__global__ __launch_bounds__(256, 2) void gemm_bt(
    const u16* __restrict__ A, const u16* __restrict__ Bt, void* __restrict__ Cout,
    const float* __restrict__ bias, const void* __restrict__ resid,
    int M, int Nn, int K){
  __shared__ __align__(16) u16 As[128*64];
  __shared__ __align__(16) u16 Bs[128*64];
  const int tid = threadIdx.x, lane = tid & 63, wave = tid >> 6;
  const int wm = wave >> 1, wn = wave & 1;
  const int l15 = lane & 15, lg = lane >> 4;
  const int bid = blockIdx.y * gridDim.x + blockIdx.x;
  const int cpx = (gridDim.x * gridDim.y) >> 3;
  const int swz = (bid & 7) * cpx + (bid >> 3);
  const int m0 = (swz / gridDim.x) * 128, n0 = (swz % gridDim.x) * 128;
  f32x4 acc[4][4] = {};
  for (int k0 = 0; k0 < K; k0 += 64){
    #pragma unroll
    for (int i = 0; i < 4; i++){
      int chunk = i*256 + tid;
      int row = chunk >> 3, seg = (chunk & 7) ^ (row & 7);
      __builtin_amdgcn_global_load_lds(
        (const __attribute__((address_space(1))) void*)&A[(size_t)(m0+row)*K + k0 + seg*8],
        (__attribute__((address_space(3))) void*)&As[(size_t)(i*256 + wave*64)*8], 16, 0, 0);
      __builtin_amdgcn_global_load_lds(
        (const __attribute__((address_space(1))) void*)&Bt[(size_t)(n0+row)*K + k0 + seg*8],
        (__attribute__((address_space(3))) void*)&Bs[(size_t)(i*256 + wave*64)*8], 16, 0, 0);
    }
    __syncthreads();
    bf16x8 af[4][2], bfr[4][2];
    #pragma unroll
    for (int i = 0; i < 4; i++){
      int ra = wm*64 + i*16 + l15, rb = wn*64 + i*16 + l15;
      #pragma unroll
      for (int kk = 0; kk < 2; kk++){
        af[i][kk]  = *(const bf16x8*)&As[ra*64 + (((kk*4 + lg) ^ (l15 & 7)) << 3)];
        bfr[i][kk] = *(const bf16x8*)&Bs[rb*64 + (((kk*4 + lg) ^ (l15 & 7)) << 3)];
      }
    }
    #pragma unroll
    for (int kk = 0; kk < 2; kk++)
      #pragma unroll
      for (int i = 0; i < 4; i++)
        #pragma unroll
        for (int j = 0; j < 4; j++)
          acc[i][j] = __builtin_amdgcn_mfma_f32_16x16x32_bf16(af[i][kk], bfr[j][kk], acc[i][j], 0, 0, 0);
    __syncthreads();
  }
  #pragma unroll
  for (int i = 0; i < 4; i++){
    int row_base = m0 + wm*64 + i*16 + lg*4;
    #pragma unroll
    for (int j = 0; j < 4; j++){
      int col = n0 + wn*64 + j*16 + l15;
      float bb = bias ? bias[col] : 0.f;
      #pragma unroll
      for (int r = 0; r < 4; r++){
        size_t idx = (size_t)(row_base + r) * Nn + col;
        float v = acc[i][j][r] + bb;
        if (EPI == 3){
          v += ((const float*)resid)[idx];
          ((u16*)Cout)[idx] = f2bf(v);
        } else if (EPI == 4){
          v += bf2f(((const u16*)resid)[idx]);
          ((float*)Cout)[idx] = v;
        } else {
          ((u16*)Cout)[idx] = f2bf(v);
        }
      }
    }
  }
}

// ---------------------------------------------------------------------------
// GEMM8PH: 256x256, 8 waves, per-wave 128x64, BK=64, dbuf 128KB LDS,
// fine 4-phase/K-tile schedule (m201 style): each phase = {ds_read subtile;
// barrier; lgkmcnt(0); sched_barrier; setprio(1); 16 MFMA; setprio(0)}.
// Staging issued in p3 (after barrier = all waves' reads of this buffer done);
// counted vmcnt(8) at tile entry keeps the next tile's loads in flight.
// EPI 0(else): +bias -> bf16   EPI 2: +bias, gelu -> bf16
template<int EPI>
__global__ __launch_bounds__(512, 2) void gemm8ph(
    const u16* __restrict__ A, const u16* __restrict__ Bt, void* __restrict__ Cout,
    const float* __restrict__ bias, int M, int Nn, int K){
  __shared__ __align__(16) u16 As0[256*64];
  __shared__ __align__(16) u16 Bs0[256*64];
  __shared__ __align__(16) u16 As1[256*64];
  __shared__ __align__(16) u16 Bs1[256*64];
  const int tid = threadIdx.x, lane = tid & 63, wave = tid >> 6;
  const int wm = wave >> 2, wn = wave & 3;    // 2 x 4 wave grid; wave C = 128x64
  const int l15 = lane & 15, lg = lane >> 4;
  const int bid = blockIdx.y * gridDim.x + blockIdx.x;
  const int cpx = (gridDim.x * gridDim.y) >> 3;
  const int swz = (bid & 7) * cpx + (bid >> 3);
  const int m0 = (swz / gridDim.x) * 256, n0 = (swz % gridDim.x) * 256;

#define STAGE8(Ad, Bd, kt) do { \
    _Pragma("unroll") \
    for (int i_ = 0; i_ < 4; i_++){ \
      int chunk_ = i_*512 + tid; \
      int row_ = chunk_ >> 3, seg_ = (chunk_ & 7) ^ (row_ & 7); \
      __builtin_amdgcn_global_load_lds( \
        (const __attribute__((address_space(1))) void*)&A[(size_t)(m0+row_)*K + ((kt) << 6) + seg_*8], \
        (__attribute__((address_space(3))) void*)&Ad[(size_t)(i_*512 + wave*64)*8], 16, 0, 0); \
      __builtin_amdgcn_global_load_lds( \
        (const __attribute__((address_space(1))) void*)&Bt[(size_t)(n0+row_)*K + ((kt) << 6) + seg_*8], \
        (__attribute__((address_space(3))) void*)&Bd[(size_t)(i_*512 + wave*64)*8], 16, 0, 0); \
    } } while(0)

#define LDSA(Ac, i, kk) (*(const bf16x8*)&Ac[(wm*128 + (i)*16 + l15)*64 + ((((kk)*4 + lg) ^ (l15 & 7)) << 3)])
#define LDSB(Bc, j, kk) (*(const bf16x8*)&Bc[(wn*64  + (j)*16 + l15)*64 + ((((kk)*4 + lg) ^ (l15 & 7)) << 3)])

#define PHASE_SYNC() do { \
    __builtin_amdgcn_s_barrier(); \
    asm volatile("s_waitcnt lgkmcnt(0)" ::: "memory"); \
    __builtin_amdgcn_sched_barrier(0); \
  } while(0)

// One K-tile: buffers (Ac,Bc); optionally stage tile ktn into (Ad,Bd) at p3.
#define TILE8(Ac, Bc, Ad, Bd, ktn, dostage, lastwait) do { \
    if (lastwait) asm volatile("s_waitcnt vmcnt(0)" ::: "memory"); \
    else          asm volatile("s_waitcnt vmcnt(8)" ::: "memory"); \
    __builtin_amdgcn_s_barrier(); \
    bf16x8 bB[4][2], bA[4][2]; \
    /* p0: B-half0 + A-half0 */ \
    _Pragma("unroll") for (int j = 0; j < 2; j++){ bB[j][0] = LDSB(Bc, j, 0); bB[j][1] = LDSB(Bc, j, 1); } \
    _Pragma("unroll") for (int i = 0; i < 4; i++){ bA[i][0] = LDSA(Ac, i, 0); bA[i][1] = LDSA(Ac, i, 1); } \
    PHASE_SYNC(); \
    __builtin_amdgcn_s_setprio(1); \
    _Pragma("unroll") for (int kk = 0; kk < 2; kk++) \
      _Pragma("unroll") for (int i = 0; i < 4; i++) \
        _Pragma("unroll") for (int j = 0; j < 2; j++) \
          acc[i][j] = __builtin_amdgcn_mfma_f32_16x16x32_bf16(bA[i][kk], bB[j][kk], acc[i][j], 0, 0, 0); \
    __builtin_amdgcn_s_setprio(0); \
    /* p1: B-half1 */ \
    _Pragma("unroll") for (int j = 2; j < 4; j++){ bB[j][0] = LDSB(Bc, j, 0); bB[j][1] = LDSB(Bc, j, 1); } \
    PHASE_SYNC(); \
    __builtin_amdgcn_s_setprio(1); \
    _Pragma("unroll") for (int kk = 0; kk < 2; kk++) \
      _Pragma("unroll") for (int i = 0; i < 4; i++) \
        _Pragma("unroll") for (int j = 2; j < 4; j++) \
          acc[i][j] = __builtin_amdgcn_mfma_f32_16x16x32_bf16(bA[i][kk], bB[j][kk], acc[i][j], 0, 0, 0); \
    __builtin_amdgcn_s_setprio(0); \
    /* p2: A-half1 (overwrite bA) */ \
    _Pragma("unroll") for (int i = 0; i < 4; i++){ bA[i][0] = LDSA(Ac, i+4, 0); bA[i][1] = LDSA(Ac, i+4, 1); } \
    PHASE_SYNC(); \
    __builtin_amdgcn_s_setprio(1); \
    _Pragma("unroll") for (int kk = 0; kk < 2; kk++) \
      _Pragma("unroll") for (int i = 0; i < 4; i++) \
        _Pragma("unroll") for (int j = 2; j < 4; j++) \
          acc[i+4][j] = __builtin_amdgcn_mfma_f32_16x16x32_bf16(bA[i][kk], bB[j][kk], acc[i+4][j], 0, 0, 0); \
    __builtin_amdgcn_s_setprio(0); \
    /* p3: stage next-next tile into freed buffer, then last quadrant */ \
    __builtin_amdgcn_s_barrier(); \
    if (dostage) STAGE8(Ad, Bd, ktn); \
    __builtin_amdgcn_s_setprio(1); \
    _Pragma("unroll") for (int kk = 0; kk < 2; kk++) \
      _Pragma("unroll") for (int i = 0; i < 4; i++) \
        _Pragma("unroll") for (int j = 0; j < 2; j++) \
          acc[i+4][j] = __builtin_amdgcn_mfma_f32_16x16x32_bf16(bA[i][kk], bB[j][kk], acc[i+4][j], 0, 0, 0); \
    __builtin_amdgcn_s_setprio(0); \
  } while(0)

  f32x4 acc[8][4] = {};
  const int nt = K >> 6;                        // 12 (even)
  STAGE8(As0, Bs0, 0);
  STAGE8(As1, Bs1, 1);
  for (int t = 0; t < nt; t += 2){
    TILE8(As0, Bs0, As0, Bs0, t + 2, (t + 2 < nt), false);
    TILE8(As1, Bs1, As1, Bs1, t + 3, (t + 3 < nt), (t + 2 >= nt));
  }
#undef TILE8
#undef PHASE_SYNC
#undef LDSA
#undef LDSB
#undef STAGE8
  #pragma unroll
  for (int i = 0; i < 8; i++){
    int row_base = m0 + wm*128 + i*16 + lg*4;
    #pragma unroll
    for (int j = 0; j < 4; j++){
      int col = n0 + wn*64 + j*16 + l15;
      float bb = bias ? bias[col] : 0.f;
      #pragma unroll
      for (int r = 0; r < 4; r++){
        size_t idx = (size_t)(row_base + r) * Nn + col;
        float v = acc[i][j][r] + bb;
        if (EPI == 2){
          float u = v + 0.044715f * v * v * v;
          float e = exp2f(-2.3022182f * u);            // exp(-1.5957691*u)
          ((u16*)Cout)[idx] = f2bf(v * __builtin_amdgcn_rcpf(1.f + e));
        } else {
          ((u16*)Cout)[idx] = f2bf(v);
        }
      }
    }
  }
}

// ---------------------------------------------------------------------------
// qkv v-part -> VT [B,H,64,512] via LDS tile transpose (XOR-swizzled cols).
__global__ void vtrans(const u16* __restrict__ qkv, u16* __restrict__ VTg){
  __shared__ u16 t[32][33];
  int bh = blockIdx.z, b = bh / 12, h = bh % 12;
  int n0 = blockIdx.x * 32, hd0 = blockIdx.y * 32;
  int tx = threadIdx.x, ty = threadIdx.y;
  #pragma unroll
  for (int i = 0; i < 4; i++){
    int n = n0 + ty + i*8;
    t[ty + i*8][tx] = qkv[((size_t)(b*512 + n))*2304 + 1536 + h*64 + hd0 + tx];
  }
  __syncthreads();
  #pragma unroll
  for (int i = 0; i < 4; i++){
    int hd = hd0 + ty + i*8;
    int col = n0 + tx;
    int tile = col >> 7, within = col & 127;
    int newcol = (tile << 7) + ((((within >> 3) ^ (hd & 7)) << 3)) + (within & 7);
    VTg[((size_t)bh*64 + hd)*512 + newcol] = t[tx][ty + i*8];
  }
}

// ---------------------------------------------------------------------------
// Attention: block = (q-tile 128) x (b,h); 4 waves, each 32 q-rows.
__global__ __launch_bounds__(256, 2) void attn_kernel(
    const u16* __restrict__ qkv, const u16* __restrict__ VTg,
    const u16* __restrict__ biasPb, u16* __restrict__ Og){
  __shared__ __align__(16) u16 Ks[128*64];
  __shared__ __align__(16) u16 Vs[64*128];
  __shared__ __align__(16) u16 Pl[4*32*136];
  const int tid = threadIdx.x, lane = tid & 63, wave = tid >> 6;
  const int l15 = lane & 15, lg = lane >> 4;
  const int bid = blockIdx.y * 4 + blockIdx.x;           // nwg = 768
  const int swz = (bid & 7) * 96 + (bid >> 3);
  const int bh = swz >> 2, b = bh / 12, h = bh % 12;
  const int q0 = (swz & 3) * 128 + wave * 32;
  const u16* Qb = qkv + (size_t)b * 512 * 2304 + h * 64;   // row stride 2304
  const u16* Kb = Qb + 768;
  const u16* Vbh = VTg + (size_t)bh * 64 * 512;
  u16* Pw = &Pl[wave * 32 * 136];

  bf16x8 qf[2][2];
  #pragma unroll
  for (int fm = 0; fm < 2; fm++)
    #pragma unroll
    for (int kk = 0; kk < 2; kk++)
      qf[fm][kk] = *(const bf16x8*)&Qb[(size_t)(q0 + fm*16 + l15)*2304 + kk*32 + lg*8];

  f32x4 O[2][4] = {};
  float lrow[2][4] = {};

  for (int kt = 0; kt < 4; kt++){
    const int k0 = kt * 128;
    bf16x8 bb[2][4];
    #pragma unroll
    for (int fm = 0; fm < 2; fm++)
      #pragma unroll
      for (int r = 0; r < 4; r++){
        int qrow = q0 + fm*16 + lg*4 + r;
        bb[fm][r] = *(const bf16x8*)&biasPb[((size_t)(b*512 + qrow)*4 + kt)*128 + l15*8];
      }
    #pragma unroll
    for (int i = 0; i < 4; i++){
      int chunk = i*256 + tid;
      int r = chunk >> 3, cc = chunk & 7;
      __builtin_amdgcn_global_load_lds(
        (const __attribute__((address_space(1))) void*)&Kb[(size_t)(k0 + r)*2304 + ((cc ^ (r & 7)) << 3)],
        (__attribute__((address_space(3))) void*)&Ks[(size_t)(i*256 + wave*64)*8],
        16, 0, 0);
    }
    #pragma unroll
    for (int i = 0; i < 4; i++){
      int chunk = i*256 + tid;
      int r = chunk >> 4, cc = chunk & 15;
      __builtin_amdgcn_global_load_lds(
        (const __attribute__((address_space(1))) void*)&Vbh[(size_t)r*512 + k0 + (cc << 3)],
        (__attribute__((address_space(3))) void*)&Vs[(size_t)(i*256 + wave*64)*8],
        16, 0, 0);
    }
    __syncthreads();

    f32x4 S[2][8] = {};
    #pragma unroll
    for (int fk = 0; fk < 8; fk++)
      #pragma unroll
      for (int kk = 0; kk < 2; kk++){
        int row = fk*16 + l15;
        bf16x8 kf = *(const bf16x8*)&Ks[row*64 + (((kk*4 + lg) ^ (l15 & 7)) << 3)];
        S[0][fk] = __builtin_amdgcn_mfma_f32_16x16x32_bf16(qf[0][kk], kf, S[0][fk], 0,0,0);
        S[1][fk] = __builtin_amdgcn_mfma_f32_16x16x32_bf16(qf[1][kk], kf, S[1][fk], 0,0,0);
      }
    #pragma unroll
    for (int fm = 0; fm < 2; fm++)
      #pragma unroll
      for (int r = 0; r < 4; r++){
        float rs = 0.f;
        #pragma unroll
        for (int fk = 0; fk < 8; fk++){
          float p = exp2f(S[fm][fk][r] + (float)bb[fm][r][fk]);
          S[fm][fk][r] = p;
          rs += p;
        }
        rs += __shfl_xor(rs, 1); rs += __shfl_xor(rs, 2);
        rs += __shfl_xor(rs, 4); rs += __shfl_xor(rs, 8);
        lrow[fm][r] += rs;
      }
    #pragma unroll
    for (int fm = 0; fm < 2; fm++)
      #pragma unroll
      for (int fk = 0; fk < 8; fk++)
        #pragma unroll
        for (int r = 0; r < 4; r++)
          Pw[(fm*16 + lg*4 + r)*136 + fk*16 + l15] = f2bf(S[fm][fk][r]);
    bf16x8 pf[2][4];
    #pragma unroll
    for (int fm = 0; fm < 2; fm++)
      #pragma unroll
      for (int kk = 0; kk < 4; kk++)
        pf[fm][kk] = *(const bf16x8*)&Pw[(fm*16 + l15)*136 + kk*32 + lg*8];
    #pragma unroll
    for (int fn = 0; fn < 4; fn++)
      #pragma unroll
      for (int kk = 0; kk < 4; kk++){
        int row = fn*16 + l15;
        bf16x8 vf = *(const bf16x8*)&Vs[row*128 + (((kk*4 + lg) ^ (l15 & 7)) << 3)];
        O[0][fn] = __builtin_amdgcn_mfma_f32_16x16x32_bf16(pf[0][kk], vf, O[0][fn], 0,0,0);
        O[1][fn] = __builtin_amdgcn_mfma_f32_16x16x32_bf16(pf[1][kk], vf, O[1][fn], 0,0,0);
      }
    __syncthreads();
  }
  #pragma unroll
  for (int fm = 0; fm < 2; fm++)
    #pragma unroll
    for (int r = 0; r < 4; r++){
      float inv = __builtin_amdgcn_rcpf(lrow[fm][r]);
      int qrow = q0 + fm*16 + lg*4 + r;
      #pragma unroll
      for (int fn = 0; fn < 4; fn++)
        Og[((size_t)b*512 + qrow)*768 + h*64 + fn*16 + l15] = f2bf(O[fm][fn][r] * inv);
    }
}

// ---------------------------------------------------------------------------
extern "C" void kernel_launch(void* const* d_in, const int* in_sizes, int n_in,
                              void* d_out, int out_size, void* d_ws, size_t ws_size,
                              hipStream_t stream){
  const float* x   = (const float*)d_in[0];
  const float* sp  = (const float*)d_in[1];
  const float* ed  = (const float*)d_in[2];
  const float* Wq  = (const float*)d_in[3];
  const float* Wk  = (const float*)d_in[4];
  const float* Wv  = (const float*)d_in[5];
  const float* bv  = (const float*)d_in[6];
  const float* Wo  = (const float*)d_in[7];
  const float* bo  = (const float*)d_in[8];
  const float* g1  = (const float*)d_in[9];
  const float* be1 = (const float*)d_in[10];
  const float* g2  = (const float*)d_in[11];
  const float* be2 = (const float*)d_in[12];
  const float* W1  = (const float*)d_in[13];
  const float* bf1 = (const float*)d_in[14];
  const float* W2  = (const float*)d_in[15];
  const float* bf2 = (const float*)d_in[16];

  char* w = (char*)d_ws;
  size_t off = 0;
  auto alloc = [&](size_t bytes)->void*{ void* p = w + off; off += (bytes + 255) & ~(size_t)255; return p; };
  u16*   Gg    = (u16*)  alloc(8192ull*3072*2);   // FFN1 out; first 37.7MB double as qkv
  u16*   qkv   = Gg;                               // [8192][2304] bf16 (dead before FFN1)
  u16*   VTg   = (u16*)  alloc(8192ull*768*2);
  u16*   h1    = (u16*)  alloc(8192ull*768*2);
  u16*   h2    = (u16*)  alloc(8192ull*768*2);
  u16*   Og    = (u16*)  alloc(8192ull*768*2);
  u16*   attb  = (u16*)  alloc(8192ull*768*2);    // bf16 att residual
  u16*   biasPb= (u16*)  alloc(16ull*512*512*2);
  u16*   WqkvT = (u16*)  alloc(2304ull*768*2);
  u16*   WoT   = (u16*)  alloc(768ull*768*2);
  u16*   W1T   = (u16*)  alloc(3072ull*768*2);
  u16*   W2T   = (u16*)  alloc(768ull*3072*2);
  float* qkvb  = (float*)alloc(2304ull*4);

  const float qscale = 0.03608439182435161f * LOG2E;  // D^-0.5 * log2e folded into Wq

  // --- prep ---
  tpose_cast<<<dim3(24,24),dim3(32,8),0,stream>>>(WqkvT,            Wq, 768, 768, qscale);
  tpose_cast<<<dim3(24,24),dim3(32,8),0,stream>>>(WqkvT + 768*768,  Wk, 768, 768, 1.f);
  tpose_cast<<<dim3(24,24),dim3(32,8),0,stream>>>(WqkvT + 1536*768, Wv, 768, 768, 1.f);
  tpose_cast<<<dim3(24,24),dim3(32,8),0,stream>>>(WoT,              Wo, 768, 768, 1.f);
  tpose_cast<<<dim3(96,24),dim3(32,8),0,stream>>>(W1T, W1, 768, 3072, 1.f);
  tpose_cast<<<dim3(24,96),dim3(32,8),0,stream>>>(W2T, W2, 3072, 768, 1.f);
  bias_prep<<<4096,256,0,stream>>>(biasPb, sp, ed);
  build_qkvb<<<9,256,0,stream>>>(qkvb, bv);

  // --- layer norms (shared stats) ---
  ln_kernel<<<2048,256,0,stream>>>(x, g1, be1, g2, be2, h1, h2);

  // --- qkv projection (256^2 8-phase: grid 9x32 = 288 blocks) ---
  gemm8ph<0><<<dim3(9,32),512,0,stream>>>(h1, WqkvT, qkv, qkvb, 8192, 2304, 768);
  vtrans<<<dim3(16,2,192),dim3(32,8),0,stream>>>(qkv, VTg);

  // --- attention ---
  attn_kernel<<<dim3(4,192),256,0,stream>>>(qkv, VTg, biasPb, Og);

  // --- output projection + residual x -> bf16 att ---
  gemm_bt<3><<<dim3(6,64),256,0,stream>>>(Og, WoT, attb, bo, x, 8192, 768, 768);

  // --- FFN ---
  gemm8ph<2><<<dim3(12,32),512,0,stream>>>(h2, W1T, Gg, bf1, 8192, 3072, 768);
  gemm_bt<4><<<dim3(6,64),256,0,stream>>>(Gg, W2T, (float*)d_out, bf2, attb, 8192, 768, 3072);
}

// Round 11
// 293.813 us; speedup vs baseline: 1.0006x; 1.0006x over previous
//
#include <hip/hip_runtime.h>
#include <math.h>

typedef unsigned short u16;
typedef __bf16 bf16x8 __attribute__((ext_vector_type(8)));
typedef float f32x4 __attribute__((ext_vector_type(4)));

__device__ __forceinline__ u16 f2bf(float f){
  union{float f; unsigned u;} v; v.f = f;
  return (u16)((v.u + 0x7fffu + ((v.u >> 16) & 1u)) >> 16);
}
__device__ __forceinline__ float bf2f(u16 b){
  union{unsigned u; float f;} v; v.u = (unsigned)b << 16; return v.f;
}

#define LOG2E 1.4426950408889634f

// ---------------------------------------------------------------------------
// One kernel for all 6 weight transposes: fp32 [R][C] -> bf16 [C][R],
// optionally row-scaled (rs[k], k = source row) and const-scaled.
__global__ void prep_weights(const float* __restrict__ Wq, const float* __restrict__ Wk,
                             const float* __restrict__ Wv, const float* __restrict__ Wo,
                             const float* __restrict__ W1, const float* __restrict__ W2,
                             const float* __restrict__ g1, const float* __restrict__ g2,
                             u16* __restrict__ WqkvT, u16* __restrict__ WoT,
                             u16* __restrict__ W1T, u16* __restrict__ W2T, float qscale){
  __shared__ float t[32][33];
  int bid = blockIdx.x;
  const float* src; u16* dst; const float* rs; float sc; int R, C, bx, by;
  if (bid < 576)      {            src=Wq; dst=WqkvT;          rs=g1;      sc=qscale; R=768;  C=768;  bx=bid%24; by=bid/24; }
  else if (bid <1152) { bid-=576;  src=Wk; dst=WqkvT+768*768;  rs=g1;      sc=1.f;    R=768;  C=768;  bx=bid%24; by=bid/24; }
  else if (bid <1728) { bid-=1152; src=Wv; dst=WqkvT+1536*768; rs=g1;      sc=1.f;    R=768;  C=768;  bx=bid%24; by=bid/24; }
  else if (bid <2304) { bid-=1728; src=Wo; dst=WoT;            rs=nullptr; sc=1.f;    R=768;  C=768;  bx=bid%24; by=bid/24; }
  else if (bid <4608) { bid-=2304; src=W1; dst=W1T;            rs=g2;      sc=1.f;    R=768;  C=3072; bx=bid%96; by=bid/96; }
  else                { bid-=4608; src=W2; dst=W2T;            rs=nullptr; sc=1.f;    R=3072; C=768;  bx=bid%24; by=bid/24; }
  int c0 = bx * 32, r0 = by * 32;
  int tx = threadIdx.x, ty = threadIdx.y;
  #pragma unroll
  for (int i = 0; i < 4; i++)
    t[ty + i*8][tx] = src[(size_t)(r0 + ty + i*8) * C + c0 + tx];
  __syncthreads();
  float fac = (rs ? rs[r0 + tx] : 1.f) * sc;   // k-index at write = r0+tx
  #pragma unroll
  for (int i = 0; i < 4; i++)
    dst[(size_t)(c0 + ty + i*8) * R + r0 + tx] = f2bf(t[tx][ty + i*8] * fac);
}

// ---------------------------------------------------------------------------
// Fold LN biases through the weights:
// qkvb[j] = (j>=1536 ? bv : 0) + sum_k be1[k]*W{q,k,v}[k][j-part]
// bf1f[c] = bf1[c] + sum_k be2[k]*W1[k][c]
__global__ void fold_bias(const float* __restrict__ Wq, const float* __restrict__ Wk,
                          const float* __restrict__ Wv, const float* __restrict__ W1,
                          const float* __restrict__ be1, const float* __restrict__ be2,
                          const float* __restrict__ bv, const float* __restrict__ bf1,
                          float* __restrict__ qkvb, float* __restrict__ bf1f){
  int j = blockIdx.x * 256 + threadIdx.x;   // 0..5375
  if (j < 2304){
    const float* W; int col; float s;
    if (j < 768)       { W = Wq; col = j;        s = 0.f; }
    else if (j < 1536) { W = Wk; col = j - 768;  s = 0.f; }
    else               { W = Wv; col = j - 1536; s = bv[col]; }
    for (int k = 0; k < 768; k++) s += be1[k] * W[(size_t)k*768 + col];
    qkvb[j] = s;
  } else if (j < 5376){
    int col = j - 2304;
    float s = bf1[col];
    for (int k = 0; k < 768; k++) s += be2[k] * W1[(size_t)k*3072 + col];
    bf1f[col] = s;
  }
}

// biasPb[b][q][kt][l15][fk] = bf16( (sp+ed)[b][q][kt*128 + fk*16 + l15] * log2e )
__global__ void bias_prep(u16* __restrict__ dst, const float* __restrict__ sp,
                          const float* __restrict__ ed){
  int t = blockIdx.x * blockDim.x + threadIdx.x;   // 16*512*128
  int row = t >> 7, c0 = (t & 127) * 4;
  size_t base = (size_t)row * 512;
  float4 s = *(const float4*)&sp[base + c0];
  float4 e = *(const float4*)&ed[base + c0];
  int kt = c0 >> 7, cw = c0 & 127, fk = cw >> 4, l0 = cw & 15;
  u16* o = dst + base + kt*128 + fk;
  o[(l0+0)*8] = f2bf((s.x+e.x)*LOG2E);
  o[(l0+1)*8] = f2bf((s.y+e.y)*LOG2E);
  o[(l0+2)*8] = f2bf((s.z+e.z)*LOG2E);
  o[(l0+3)*8] = f2bf((s.w+e.w)*LOG2E);
}

// ---------------------------------------------------------------------------
// LayerNorm core only: hn = (x - mu) * rsqrt(var + eps)   (g/b folded into W)
__global__ __launch_bounds__(256) void ln_kernel(
    const float* __restrict__ x, u16* __restrict__ hn){
  const int lane = threadIdx.x & 63, wave = threadIdx.x >> 6;
  const int row = blockIdx.x * 4 + wave;
  const float4* xr = (const float4*)(x + (size_t)row * 768);
  float4 v[3];
  float sum = 0.f, sq = 0.f;
  #pragma unroll
  for (int c = 0; c < 3; c++){
    v[c] = xr[lane + 64*c];
    sum += v[c].x + v[c].y + v[c].z + v[c].w;
    sq  += v[c].x*v[c].x + v[c].y*v[c].y + v[c].z*v[c].z + v[c].w*v[c].w;
  }
  #pragma unroll
  for (int d = 1; d < 64; d <<= 1){ sum += __shfl_xor(sum, d); sq += __shfl_xor(sq, d); }
  float mu  = sum * (1.f/768.f);
  float var = sq * (1.f/768.f) - mu*mu;
  float rs  = rsqrtf(var + 1e-5f);
  #pragma unroll
  for (int c = 0; c < 3; c++){
    int f4 = lane + 64*c;
    ushort4 o{f2bf((v[c].x-mu)*rs), f2bf((v[c].y-mu)*rs),
              f2bf((v[c].z-mu)*rs), f2bf((v[c].w-mu)*rs)};
    ((ushort4*)(hn + (size_t)row*768))[f4] = o;
  }
}

// ---------------------------------------------------------------------------
// GEMM: C[M,N] = A[M,K](bf16) @ Bt[N,K](bf16)^T, fp32 accum.  Proven R4
// structure: 128x128 tile, 64x64/wave, BK=64, XOR-swizzled single-buffer LDS
// (32KB -> 5 blocks/CU), XCD-aware block swizzle, 2 barriers per K-step.
// EPI 0: +bias -> bf16            EPI 2: +bias, gelu -> bf16
// EPI 3: +bias +resid(f32) -> bf16   EPI 4: +bias +resid(bf16) -> f32
template<int EPI>
__global__ __launch_bounds__(256, 2) void gemm_bt(
    const u16* __restrict__ A, const u16* __restrict__ Bt, void* __restrict__ Cout,
    const float* __restrict__ bias, const void* __restrict__ resid,
    int M, int Nn, int K){
  __shared__ __align__(16) u16 As[128*64];
  __shared__ __align__(16) u16 Bs[128*64];
  const int tid = threadIdx.x, lane = tid & 63, wave = tid >> 6;
  const int wm = wave >> 1, wn = wave & 1;
  const int l15 = lane & 15, lg = lane >> 4;
  const int bid = blockIdx.y * gridDim.x + blockIdx.x;
  const int cpx = (gridDim.x * gridDim.y) >> 3;
  const int swz = (bid & 7) * cpx + (bid >> 3);
  const int m0 = (swz / gridDim.x) * 128, n0 = (swz % gridDim.x) * 128;
  f32x4 acc[4][4] = {};
  for (int k0 = 0; k0 < K; k0 += 64){
    #pragma unroll
    for (int i = 0; i < 4; i++){
      int chunk = i*256 + tid;
      int row = chunk >> 3, seg = (chunk & 7) ^ (row & 7);
      __builtin_amdgcn_global_load_lds(
        (const __attribute__((address_space(1))) void*)&A[(size_t)(m0+row)*K + k0 + seg*8],
        (__attribute__((address_space(3))) void*)&As[(size_t)(i*256 + wave*64)*8], 16, 0, 0);
      __builtin_amdgcn_global_load_lds(
        (const __attribute__((address_space(1))) void*)&Bt[(size_t)(n0+row)*K + k0 + seg*8],
        (__attribute__((address_space(3))) void*)&Bs[(size_t)(i*256 + wave*64)*8], 16, 0, 0);
    }
    __syncthreads();
    bf16x8 af[4][2], bfr[4][2];
    #pragma unroll
    for (int i = 0; i < 4; i++){
      int ra = wm*64 + i*16 + l15, rb = wn*64 + i*16 + l15;
      #pragma unroll
      for (int kk = 0; kk < 2; kk++){
        af[i][kk]  = *(const bf16x8*)&As[ra*64 + (((kk*4 + lg) ^ (l15 & 7)) << 3)];
        bfr[i][kk] = *(const bf16x8*)&Bs[rb*64 + (((kk*4 + lg) ^ (l15 & 7)) << 3)];
      }
    }
    #pragma unroll
    for (int kk = 0; kk < 2; kk++)
      #pragma unroll
      for (int i = 0; i < 4; i++)
        #pragma unroll
        for (int j = 0; j < 4; j++)
          acc[i][j] = __builtin_amdgcn_mfma_f32_16x16x32_bf16(af[i][kk], bfr[j][kk], acc[i][j], 0, 0, 0);
    __syncthreads();
  }
  #pragma unroll
  for (int i = 0; i < 4; i++){
    int row_base = m0 + wm*64 + i*16 + lg*4;
    #pragma unroll
    for (int j = 0; j < 4; j++){
      int col = n0 + wn*64 + j*16 + l15;
      float bb = bias ? bias[col] : 0.f;
      #pragma unroll
      for (int r = 0; r < 4; r++){
        size_t idx = (size_t)(row_base + r) * Nn + col;
        float v = acc[i][j][r] + bb;
        if (EPI == 3){
          v += ((const float*)resid)[idx];
          ((u16*)Cout)[idx] = f2bf(v);
        } else if (EPI == 4){
          v += bf2f(((const u16*)resid)[idx]);
          ((float*)Cout)[idx] = v;
        } else if (EPI == 2){
          float u = v + 0.044715f * v * v * v;
          float e = exp2f(-2.3022182f * u);          // exp(-1.5957691*u)
          ((u16*)Cout)[idx] = f2bf(v * __builtin_amdgcn_rcpf(1.f + e));
        } else {
          ((u16*)Cout)[idx] = f2bf(v);
        }
      }
    }
  }
}

// ---------------------------------------------------------------------------
// qkv v-part -> VT [B,H,64,512] via LDS tile transpose (XOR-swizzled cols).
__global__ void vtrans(const u16* __restrict__ qkv, u16* __restrict__ VTg){
  __shared__ u16 t[32][33];
  int bh = blockIdx.z, b = bh / 12, h = bh % 12;
  int n0 = blockIdx.x * 32, hd0 = blockIdx.y * 32;
  int tx = threadIdx.x, ty = threadIdx.y;
  #pragma unroll
  for (int i = 0; i < 4; i++){
    int n = n0 + ty + i*8;
    t[ty + i*8][tx] = qkv[((size_t)(b*512 + n))*2304 + 1536 + h*64 + hd0 + tx];
  }
  __syncthreads();
  #pragma unroll
  for (int i = 0; i < 4; i++){
    int hd = hd0 + ty + i*8;
    int col = n0 + tx;
    int tile = col >> 7, within = col & 127;
    int newcol = (tile << 7) + ((((within >> 3) ^ (hd & 7)) << 3)) + (within & 7);
    VTg[((size_t)bh*64 + hd)*512 + newcol] = t[tx][ty + i*8];
  }
}

// ---------------------------------------------------------------------------
// Attention: block = (q-tile 128) x (b,h); 4 waves, each 32 q-rows.
// K/V LDS-staged per block per kt; bf16 bias; unshifted exp2 softmax.
__global__ __launch_bounds__(256, 2) void attn_kernel(
    const u16* __restrict__ qkv, const u16* __restrict__ VTg,
    const u16* __restrict__ biasPb, u16* __restrict__ Og){
  __shared__ __align__(16) u16 Ks[128*64];
  __shared__ __align__(16) u16 Vs[64*128];
  __shared__ __align__(16) u16 Pl[4*32*136];
  const int tid = threadIdx.x, lane = tid & 63, wave = tid >> 6;
  const int l15 = lane & 15, lg = lane >> 4;
  const int bid = blockIdx.y * 4 + blockIdx.x;           // nwg = 768
  const int swz = (bid & 7) * 96 + (bid >> 3);
  const int bh = swz >> 2, b = bh / 12, h = bh % 12;
  const int q0 = (swz & 3) * 128 + wave * 32;
  const u16* Qb = qkv + (size_t)b * 512 * 2304 + h * 64;   // row stride 2304
  const u16* Kb = Qb + 768;
  const u16* Vbh = VTg + (size_t)bh * 64 * 512;
  u16* Pw = &Pl[wave * 32 * 136];

  bf16x8 qf[2][2];
  #pragma unroll
  for (int fm = 0; fm < 2; fm++)
    #pragma unroll
    for (int kk = 0; kk < 2; kk++)
      qf[fm][kk] = *(const bf16x8*)&Qb[(size_t)(q0 + fm*16 + l15)*2304 + kk*32 + lg*8];

  f32x4 O[2][4] = {};
  float lrow[2][4] = {};

  for (int kt = 0; kt < 4; kt++){
    const int k0 = kt * 128;
    bf16x8 bb[2][4];
    #pragma unroll
    for (int fm = 0; fm < 2; fm++)
      #pragma unroll
      for (int r = 0; r < 4; r++){
        int qrow = q0 + fm*16 + lg*4 + r;
        bb[fm][r] = *(const bf16x8*)&biasPb[((size_t)(b*512 + qrow)*4 + kt)*128 + l15*8];
      }
    #pragma unroll
    for (int i = 0; i < 4; i++){
      int chunk = i*256 + tid;
      int r = chunk >> 3, cc = chunk & 7;
      __builtin_amdgcn_global_load_lds(
        (const __attribute__((address_space(1))) void*)&Kb[(size_t)(k0 + r)*2304 + ((cc ^ (r & 7)) << 3)],
        (__attribute__((address_space(3))) void*)&Ks[(size_t)(i*256 + wave*64)*8],
        16, 0, 0);
    }
    #pragma unroll
    for (int i = 0; i < 4; i++){
      int chunk = i*256 + tid;
      int r = chunk >> 4, cc = chunk & 15;
      __builtin_amdgcn_global_load_lds(
        (const __attribute__((address_space(1))) void*)&Vbh[(size_t)r*512 + k0 + (cc << 3)],
        (__attribute__((address_space(3))) void*)&Vs[(size_t)(i*256 + wave*64)*8],
        16, 0, 0);
    }
    __syncthreads();

    f32x4 S[2][8] = {};
    #pragma unroll
    for (int fk = 0; fk < 8; fk++)
      #pragma unroll
      for (int kk = 0; kk < 2; kk++){
        int row = fk*16 + l15;
        bf16x8 kf = *(const bf16x8*)&Ks[row*64 + (((kk*4 + lg) ^ (l15 & 7)) << 3)];
        S[0][fk] = __builtin_amdgcn_mfma_f32_16x16x32_bf16(qf[0][kk], kf, S[0][fk], 0,0,0);
        S[1][fk] = __builtin_amdgcn_mfma_f32_16x16x32_bf16(qf[1][kk], kf, S[1][fk], 0,0,0);
      }
    #pragma unroll
    for (int fm = 0; fm < 2; fm++)
      #pragma unroll
      for (int r = 0; r < 4; r++){
        float rs = 0.f;
        #pragma unroll
        for (int fk = 0; fk < 8; fk++){
          float p = exp2f(S[fm][fk][r] + (float)bb[fm][r][fk]);
          S[fm][fk][r] = p;
          rs += p;
        }
        rs += __shfl_xor(rs, 1); rs += __shfl_xor(rs, 2);
        rs += __shfl_xor(rs, 4); rs += __shfl_xor(rs, 8);
        lrow[fm][r] += rs;
      }
    #pragma unroll
    for (int fm = 0; fm < 2; fm++)
      #pragma unroll
      for (int fk = 0; fk < 8; fk++)
        #pragma unroll
        for (int r = 0; r < 4; r++)
          Pw[(fm*16 + lg*4 + r)*136 + fk*16 + l15] = f2bf(S[fm][fk][r]);
    bf16x8 pf[2][4];
    #pragma unroll
    for (int fm = 0; fm < 2; fm++)
      #pragma unroll
      for (int kk = 0; kk < 4; kk++)
        pf[fm][kk] = *(const bf16x8*)&Pw[(fm*16 + l15)*136 + kk*32 + lg*8];
    #pragma unroll
    for (int fn = 0; fn < 4; fn++)
      #pragma unroll
      for (int kk = 0; kk < 4; kk++){
        int row = fn*16 + l15;
        bf16x8 vf = *(const bf16x8*)&Vs[row*128 + (((kk*4 + lg) ^ (l15 & 7)) << 3)];
        O[0][fn] = __builtin_amdgcn_mfma_f32_16x16x32_bf16(pf[0][kk], vf, O[0][fn], 0,0,0);
        O[1][fn] = __builtin_amdgcn_mfma_f32_16x16x32_bf16(pf[1][kk], vf, O[1][fn], 0,0,0);
      }
    __syncthreads();
  }
  #pragma unroll
  for (int fm = 0; fm < 2; fm++)
    #pragma unroll
    for (int r = 0; r < 4; r++){
      float inv = __builtin_amdgcn_rcpf(lrow[fm][r]);
      int qrow = q0 + fm*16 + lg*4 + r;
      #pragma unroll
      for (int fn = 0; fn < 4; fn++)
        Og[((size_t)b*512 + qrow)*768 + h*64 + fn*16 + l15] = f2bf(O[fm][fn][r] * inv);
    }
}

// ---------------------------------------------------------------------------
extern "C" void kernel_launch(void* const* d_in, const int* in_sizes, int n_in,
                              void* d_out, int out_size, void* d_ws, size_t ws_size,
                              hipStream_t stream){
  const float* x   = (const float*)d_in[0];
  const float* sp  = (const float*)d_in[1];
  const float* ed  = (const float*)d_in[2];
  const float* Wq  = (const float*)d_in[3];
  const float* Wk  = (const float*)d_in[4];
  const float* Wv  = (const float*)d_in[5];
  const float* bv  = (const float*)d_in[6];
  const float* Wo  = (const float*)d_in[7];
  const float* bo  = (const float*)d_in[8];
  const float* g1  = (const float*)d_in[9];
  const float* be1 = (const float*)d_in[10];
  const float* g2  = (const float*)d_in[11];
  const float* be2 = (const float*)d_in[12];
  const float* W1  = (const float*)d_in[13];
  const float* bf1 = (const float*)d_in[14];
  const float* W2  = (const float*)d_in[15];
  const float* bf2 = (const float*)d_in[16];

  char* w = (char*)d_ws;
  size_t off = 0;
  auto alloc = [&](size_t bytes)->void*{ void* p = w + off; off += (bytes + 255) & ~(size_t)255; return p; };
  u16*   Gg    = (u16*)  alloc(8192ull*3072*2);   // FFN1 out; first 37.7MB double as qkv
  u16*   qkv   = Gg;                               // [8192][2304] bf16 (dead before FFN1)
  u16*   VTg   = (u16*)  alloc(8192ull*768*2);
  u16*   hn    = (u16*)  alloc(8192ull*768*2);    // shared LN core (g/b folded into W)
  u16*   Og    = (u16*)  alloc(8192ull*768*2);
  u16*   attb  = (u16*)  alloc(8192ull*768*2);    // bf16 att residual
  u16*   biasPb= (u16*)  alloc(16ull*512*512*2);
  u16*   WqkvT = (u16*)  alloc(2304ull*768*2);
  u16*   WoT   = (u16*)  alloc(768ull*768*2);
  u16*   W1T   = (u16*)  alloc(3072ull*768*2);
  u16*   W2T   = (u16*)  alloc(768ull*3072*2);
  float* qkvb  = (float*)alloc(2304ull*4);
  float* bf1f  = (float*)alloc(3072ull*4);

  const float qscale = 0.03608439182435161f * LOG2E;  // D^-0.5 * log2e folded into Wq

  // --- prep (2 launches instead of 8) ---
  prep_weights<<<6912, dim3(32,8), 0, stream>>>(Wq, Wk, Wv, Wo, W1, W2, g1, g2,
                                                WqkvT, WoT, W1T, W2T, qscale);
  fold_bias<<<21, 256, 0, stream>>>(Wq, Wk, Wv, W1, be1, be2, bv, bf1, qkvb, bf1f);
  bias_prep<<<4096, 256, 0, stream>>>(biasPb, sp, ed);

  // --- layer norm core (single tensor, g/b folded) ---
  ln_kernel<<<2048, 256, 0, stream>>>(x, hn);

  // --- qkv projection ---
  gemm_bt<0><<<dim3(18,64),256,0,stream>>>(hn, WqkvT, qkv, qkvb, nullptr, 8192, 2304, 768);
  vtrans<<<dim3(16,2,192),dim3(32,8),0,stream>>>(qkv, VTg);

  // --- attention ---
  attn_kernel<<<dim3(4,192),256,0,stream>>>(qkv, VTg, biasPb, Og);

  // --- output projection + residual x -> bf16 att ---
  gemm_bt<3><<<dim3(6,64),256,0,stream>>>(Og, WoT, attb, bo, x, 8192, 768, 768);

  // --- FFN ---
  gemm_bt<2><<<dim3(24,64),256,0,stream>>>(hn, W1T, Gg, bf1f, nullptr, 8192, 3072, 768);
  gemm_bt<4><<<dim3(6,64),256,0,stream>>>(Gg, W2T, (float*)d_out, bf2, attb, 8192, 768, 3072);
}

// Round 12
// 256.802 us; speedup vs baseline: 1.1449x; 1.1441x over previous
//
#include <hip/hip_runtime.h>
#include <math.h>

typedef unsigned short u16;
typedef __bf16 bf16x8 __attribute__((ext_vector_type(8)));
typedef float f32x4 __attribute__((ext_vector_type(4)));

__device__ __forceinline__ u16 f2bf(float f){
  union{float f; unsigned u;} v; v.f = f;
  return (u16)((v.u + 0x7fffu + ((v.u >> 16) & 1u)) >> 16);
}
__device__ __forceinline__ float bf2f(u16 b){
  union{unsigned u; float f;} v; v.u = (unsigned)b << 16; return v.f;
}

#define LOG2E 1.4426950408889634f

// ---------------------------------------------------------------------------
// One kernel for all 6 weight transposes: fp32 [R][C] -> bf16 [C][R],
// optionally row-scaled (rs[k], k = source row) and const-scaled.
__global__ void prep_weights(const float* __restrict__ Wq, const float* __restrict__ Wk,
                             const float* __restrict__ Wv, const float* __restrict__ Wo,
                             const float* __restrict__ W1, const float* __restrict__ W2,
                             const float* __restrict__ g1, const float* __restrict__ g2,
                             u16* __restrict__ WqkvT, u16* __restrict__ WoT,
                             u16* __restrict__ W1T, u16* __restrict__ W2T, float qscale){
  __shared__ float t[32][33];
  int bid = blockIdx.x;
  const float* src; u16* dst; const float* rs; float sc; int R, C, bx, by;
  if (bid < 576)      {            src=Wq; dst=WqkvT;          rs=g1;      sc=qscale; R=768;  C=768;  bx=bid%24; by=bid/24; }
  else if (bid <1152) { bid-=576;  src=Wk; dst=WqkvT+768*768;  rs=g1;      sc=1.f;    R=768;  C=768;  bx=bid%24; by=bid/24; }
  else if (bid <1728) { bid-=1152; src=Wv; dst=WqkvT+1536*768; rs=g1;      sc=1.f;    R=768;  C=768;  bx=bid%24; by=bid/24; }
  else if (bid <2304) { bid-=1728; src=Wo; dst=WoT;            rs=nullptr; sc=1.f;    R=768;  C=768;  bx=bid%24; by=bid/24; }
  else if (bid <4608) { bid-=2304; src=W1; dst=W1T;            rs=g2;      sc=1.f;    R=768;  C=3072; bx=bid%96; by=bid/96; }
  else                { bid-=4608; src=W2; dst=W2T;            rs=nullptr; sc=1.f;    R=3072; C=768;  bx=bid%24; by=bid/24; }
  int c0 = bx * 32, r0 = by * 32;
  int tx = threadIdx.x, ty = threadIdx.y;
  #pragma unroll
  for (int i = 0; i < 4; i++)
    t[ty + i*8][tx] = src[(size_t)(r0 + ty + i*8) * C + c0 + tx];
  __syncthreads();
  float fac = (rs ? rs[r0 + tx] : 1.f) * sc;   // k-index at write = r0+tx
  #pragma unroll
  for (int i = 0; i < 4; i++)
    dst[(size_t)(c0 + ty + i*8) * R + r0 + tx] = f2bf(t[tx][ty + i*8] * fac);
}

// ---------------------------------------------------------------------------
// Parallel bias folding (two GEMVs). Block = 64 cols x 4 k-groups; coalesced.
// qkvb[j] = (j>=1536 ? bv : 0) + sum_k be1[k]*W{q,k,v}[k][col]
// bf1f[c] = bf1[c] + sum_k be2[k]*W1[k][c]
__global__ __launch_bounds__(256) void fold_bias(
    const float* __restrict__ Wq, const float* __restrict__ Wk,
    const float* __restrict__ Wv, const float* __restrict__ W1,
    const float* __restrict__ be1, const float* __restrict__ be2,
    const float* __restrict__ bv, const float* __restrict__ bf1,
    float* __restrict__ qkvb, float* __restrict__ bf1f){
  __shared__ float red[4][64];
  int tx = threadIdx.x & 63, ty = threadIdx.x >> 6;
  int j = blockIdx.x * 64 + tx;                  // 0..5375 (grid 84, uniform per block)
  const float* W; int col, stride; const float* bvec;
  if (j < 768)       { W = Wq; col = j;        stride = 768;  bvec = be1; }
  else if (j < 1536) { W = Wk; col = j - 768;  stride = 768;  bvec = be1; }
  else if (j < 2304) { W = Wv; col = j - 1536; stride = 768;  bvec = be1; }
  else               { W = W1; col = j - 2304; stride = 3072; bvec = be2; }
  float s = 0.f;
  for (int k = ty * 192; k < (ty + 1) * 192; k++)
    s += bvec[k] * W[(size_t)k * stride + col];
  red[ty][tx] = s;
  __syncthreads();
  if (ty == 0){
    s = red[0][tx] + red[1][tx] + red[2][tx] + red[3][tx];
    if (j < 1536)      qkvb[j] = s;
    else if (j < 2304) qkvb[j] = s + bv[col];
    else               bf1f[col] = s + bf1[col];
  }
}

// biasPb[b][q][kt][l15][fk] = bf16( (sp+ed)[b][q][kt*128 + fk*16 + l15] * log2e )
__global__ void bias_prep(u16* __restrict__ dst, const float* __restrict__ sp,
                          const float* __restrict__ ed){
  int t = blockIdx.x * blockDim.x + threadIdx.x;   // 16*512*128
  int row = t >> 7, c0 = (t & 127) * 4;
  size_t base = (size_t)row * 512;
  float4 s = *(const float4*)&sp[base + c0];
  float4 e = *(const float4*)&ed[base + c0];
  int kt = c0 >> 7, cw = c0 & 127, fk = cw >> 4, l0 = cw & 15;
  u16* o = dst + base + kt*128 + fk;
  o[(l0+0)*8] = f2bf((s.x+e.x)*LOG2E);
  o[(l0+1)*8] = f2bf((s.y+e.y)*LOG2E);
  o[(l0+2)*8] = f2bf((s.z+e.z)*LOG2E);
  o[(l0+3)*8] = f2bf((s.w+e.w)*LOG2E);
}

// ---------------------------------------------------------------------------
// LayerNorm core only: hn = (x - mu) * rsqrt(var + eps)   (g/b folded into W)
__global__ __launch_bounds__(256) void ln_kernel(
    const float* __restrict__ x, u16* __restrict__ hn){
  const int lane = threadIdx.x & 63, wave = threadIdx.x >> 6;
  const int row = blockIdx.x * 4 + wave;
  const float4* xr = (const float4*)(x + (size_t)row * 768);
  float4 v[3];
  float sum = 0.f, sq = 0.f;
  #pragma unroll
  for (int c = 0; c < 3; c++){
    v[c] = xr[lane + 64*c];
    sum += v[c].x + v[c].y + v[c].z + v[c].w;
    sq  += v[c].x*v[c].x + v[c].y*v[c].y + v[c].z*v[c].z + v[c].w*v[c].w;
  }
  #pragma unroll
  for (int d = 1; d < 64; d <<= 1){ sum += __shfl_xor(sum, d); sq += __shfl_xor(sq, d); }
  float mu  = sum * (1.f/768.f);
  float var = sq * (1.f/768.f) - mu*mu;
  float rs  = rsqrtf(var + 1e-5f);
  #pragma unroll
  for (int c = 0; c < 3; c++){
    int f4 = lane + 64*c;
    ushort4 o{f2bf((v[c].x-mu)*rs), f2bf((v[c].y-mu)*rs),
              f2bf((v[c].z-mu)*rs), f2bf((v[c].w-mu)*rs)};
    ((ushort4*)(hn + (size_t)row*768))[f4] = o;
  }
}

// ---------------------------------------------------------------------------
// GEMM: C[M,N] = A[M,K](bf16) @ Bt[N,K](bf16)^T, fp32 accum.  Proven R4
// structure: 128x128 tile, 64x64/wave, BK=64, XOR-swizzled single-buffer LDS,
// XCD-aware block swizzle, 2 barriers per K-step.
// EPI 0: +bias -> bf16            EPI 2: +bias, gelu -> bf16
// EPI 3: +bias +resid(f32) -> bf16   EPI 4: +bias +resid(bf16) -> f32
// EPI 5: qkv fused epilogue — cols<1536 row-major bf16; cols>=1536 write
//        V directly into the swizzled VT[bh][hd][n'] layout (vtrans fused).
template<int EPI>
__global__ __launch_bounds__(256, 2) void gemm_bt(
    const u16* __restrict__ A, const u16* __restrict__ Bt, void* __restrict__ Cout,
    const float* __restrict__ bias, const void* __restrict__ resid,
    u16* __restrict__ vt, int M, int Nn, int K){
  __shared__ __align__(16) u16 As[128*64];
  __shared__ __align__(16) u16 Bs[128*64];
  const int tid = threadIdx.x, lane = tid & 63, wave = tid >> 6;
  const int wm = wave >> 1, wn = wave & 1;
  const int l15 = lane & 15, lg = lane >> 4;
  const int bid = blockIdx.y * gridDim.x + blockIdx.x;
  const int cpx = (gridDim.x * gridDim.y) >> 3;
  const int swz = (bid & 7) * cpx + (bid >> 3);
  const int m0 = (swz / gridDim.x) * 128, n0 = (swz % gridDim.x) * 128;
  f32x4 acc[4][4] = {};
  for (int k0 = 0; k0 < K; k0 += 64){
    #pragma unroll
    for (int i = 0; i < 4; i++){
      int chunk = i*256 + tid;
      int row = chunk >> 3, seg = (chunk & 7) ^ (row & 7);
      __builtin_amdgcn_global_load_lds(
        (const __attribute__((address_space(1))) void*)&A[(size_t)(m0+row)*K + k0 + seg*8],
        (__attribute__((address_space(3))) void*)&As[(size_t)(i*256 + wave*64)*8], 16, 0, 0);
      __builtin_amdgcn_global_load_lds(
        (const __attribute__((address_space(1))) void*)&Bt[(size_t)(n0+row)*K + k0 + seg*8],
        (__attribute__((address_space(3))) void*)&Bs[(size_t)(i*256 + wave*64)*8], 16, 0, 0);
    }
    __syncthreads();
    bf16x8 af[4][2], bfr[4][2];
    #pragma unroll
    for (int i = 0; i < 4; i++){
      int ra = wm*64 + i*16 + l15, rb = wn*64 + i*16 + l15;
      #pragma unroll
      for (int kk = 0; kk < 2; kk++){
        af[i][kk]  = *(const bf16x8*)&As[ra*64 + (((kk*4 + lg) ^ (l15 & 7)) << 3)];
        bfr[i][kk] = *(const bf16x8*)&Bs[rb*64 + (((kk*4 + lg) ^ (l15 & 7)) << 3)];
      }
    }
    #pragma unroll
    for (int kk = 0; kk < 2; kk++)
      #pragma unroll
      for (int i = 0; i < 4; i++)
        #pragma unroll
        for (int j = 0; j < 4; j++)
          acc[i][j] = __builtin_amdgcn_mfma_f32_16x16x32_bf16(af[i][kk], bfr[j][kk], acc[i][j], 0, 0, 0);
    __syncthreads();
  }
  #pragma unroll
  for (int i = 0; i < 4; i++){
    int row_base = m0 + wm*64 + i*16 + lg*4;
    #pragma unroll
    for (int j = 0; j < 4; j++){
      int col = n0 + wn*64 + j*16 + l15;
      float bcol = bias ? bias[col] : 0.f;
      if (EPI == 5 && col >= 1536){
        // V part -> VT[bh][hd][n'] (swizzled); 4 rows are contiguous n
        int hv = (col - 1536) >> 6, hd = (col - 1536) & 63;
        int b = row_base >> 9, n = row_base & 511;
        int within = n & 127;
        int newn = (n & ~127) + ((((within >> 3) ^ (hd & 7)) << 3)) + (within & 7);
        ushort4 ov{f2bf(acc[i][j][0] + bcol), f2bf(acc[i][j][1] + bcol),
                   f2bf(acc[i][j][2] + bcol), f2bf(acc[i][j][3] + bcol)};
        *(ushort4*)&vt[(((size_t)(b*12 + hv)*64 + hd) << 9) + newn] = ov;
        continue;
      }
      #pragma unroll
      for (int r = 0; r < 4; r++){
        size_t idx = (size_t)(row_base + r) * Nn + col;
        float v = acc[i][j][r] + bcol;
        if (EPI == 3){
          v += ((const float*)resid)[idx];
          ((u16*)Cout)[idx] = f2bf(v);
        } else if (EPI == 4){
          v += bf2f(((const u16*)resid)[idx]);
          ((float*)Cout)[idx] = v;
        } else if (EPI == 2){
          float u = v + 0.044715f * v * v * v;
          float e = exp2f(-2.3022182f * u);          // exp(-1.5957691*u)
          ((u16*)Cout)[idx] = f2bf(v * __builtin_amdgcn_rcpf(1.f + e));
        } else {
          ((u16*)Cout)[idx] = f2bf(v);               // EPI 0 and EPI 5 (Q/K part)
        }
      }
    }
  }
}

// ---------------------------------------------------------------------------
// Attention: block = (q-tile 128) x (b,h); 4 waves, each 32 q-rows.
// K/V LDS-staged per block per kt; bf16 bias; unshifted exp2 softmax.
__global__ __launch_bounds__(256, 2) void attn_kernel(
    const u16* __restrict__ qkv, const u16* __restrict__ VTg,
    const u16* __restrict__ biasPb, u16* __restrict__ Og){
  __shared__ __align__(16) u16 Ks[128*64];
  __shared__ __align__(16) u16 Vs[64*128];
  __shared__ __align__(16) u16 Pl[4*32*136];
  const int tid = threadIdx.x, lane = tid & 63, wave = tid >> 6;
  const int l15 = lane & 15, lg = lane >> 4;
  const int bid = blockIdx.y * 4 + blockIdx.x;           // nwg = 768
  const int swz = (bid & 7) * 96 + (bid >> 3);
  const int bh = swz >> 2, b = bh / 12, h = bh % 12;
  const int q0 = (swz & 3) * 128 + wave * 32;
  const u16* Qb = qkv + (size_t)b * 512 * 2304 + h * 64;   // row stride 2304
  const u16* Kb = Qb + 768;
  const u16* Vbh = VTg + (size_t)bh * 64 * 512;
  u16* Pw = &Pl[wave * 32 * 136];

  bf16x8 qf[2][2];
  #pragma unroll
  for (int fm = 0; fm < 2; fm++)
    #pragma unroll
    for (int kk = 0; kk < 2; kk++)
      qf[fm][kk] = *(const bf16x8*)&Qb[(size_t)(q0 + fm*16 + l15)*2304 + kk*32 + lg*8];

  f32x4 O[2][4] = {};
  float lrow[2][4] = {};

  for (int kt = 0; kt < 4; kt++){
    const int k0 = kt * 128;
    bf16x8 bb[2][4];
    #pragma unroll
    for (int fm = 0; fm < 2; fm++)
      #pragma unroll
      for (int r = 0; r < 4; r++){
        int qrow = q0 + fm*16 + lg*4 + r;
        bb[fm][r] = *(const bf16x8*)&biasPb[((size_t)(b*512 + qrow)*4 + kt)*128 + l15*8];
      }
    #pragma unroll
    for (int i = 0; i < 4; i++){
      int chunk = i*256 + tid;
      int r = chunk >> 3, cc = chunk & 7;
      __builtin_amdgcn_global_load_lds(
        (const __attribute__((address_space(1))) void*)&Kb[(size_t)(k0 + r)*2304 + ((cc ^ (r & 7)) << 3)],
        (__attribute__((address_space(3))) void*)&Ks[(size_t)(i*256 + wave*64)*8],
        16, 0, 0);
    }
    #pragma unroll
    for (int i = 0; i < 4; i++){
      int chunk = i*256 + tid;
      int r = chunk >> 4, cc = chunk & 15;
      __builtin_amdgcn_global_load_lds(
        (const __attribute__((address_space(1))) void*)&Vbh[(size_t)r*512 + k0 + (cc << 3)],
        (__attribute__((address_space(3))) void*)&Vs[(size_t)(i*256 + wave*64)*8],
        16, 0, 0);
    }
    __syncthreads();

    f32x4 S[2][8] = {};
    #pragma unroll
    for (int fk = 0; fk < 8; fk++)
      #pragma unroll
      for (int kk = 0; kk < 2; kk++){
        int row = fk*16 + l15;
        bf16x8 kf = *(const bf16x8*)&Ks[row*64 + (((kk*4 + lg) ^ (l15 & 7)) << 3)];
        S[0][fk] = __builtin_amdgcn_mfma_f32_16x16x32_bf16(qf[0][kk], kf, S[0][fk], 0,0,0);
        S[1][fk] = __builtin_amdgcn_mfma_f32_16x16x32_bf16(qf[1][kk], kf, S[1][fk], 0,0,0);
      }
    #pragma unroll
    for (int fm = 0; fm < 2; fm++)
      #pragma unroll
      for (int r = 0; r < 4; r++){
        float rs = 0.f;
        #pragma unroll
        for (int fk = 0; fk < 8; fk++){
          float p = exp2f(S[fm][fk][r] + (float)bb[fm][r][fk]);
          S[fm][fk][r] = p;
          rs += p;
        }
        rs += __shfl_xor(rs, 1); rs += __shfl_xor(rs, 2);
        rs += __shfl_xor(rs, 4); rs += __shfl_xor(rs, 8);
        lrow[fm][r] += rs;
      }
    #pragma unroll
    for (int fm = 0; fm < 2; fm++)
      #pragma unroll
      for (int fk = 0; fk < 8; fk++)
        #pragma unroll
        for (int r = 0; r < 4; r++)
          Pw[(fm*16 + lg*4 + r)*136 + fk*16 + l15] = f2bf(S[fm][fk][r]);
    bf16x8 pf[2][4];
    #pragma unroll
    for (int fm = 0; fm < 2; fm++)
      #pragma unroll
      for (int kk = 0; kk < 4; kk++)
        pf[fm][kk] = *(const bf16x8*)&Pw[(fm*16 + l15)*136 + kk*32 + lg*8];
    #pragma unroll
    for (int fn = 0; fn < 4; fn++)
      #pragma unroll
      for (int kk = 0; kk < 4; kk++){
        int row = fn*16 + l15;
        bf16x8 vf = *(const bf16x8*)&Vs[row*128 + (((kk*4 + lg) ^ (l15 & 7)) << 3)];
        O[0][fn] = __builtin_amdgcn_mfma_f32_16x16x32_bf16(pf[0][kk], vf, O[0][fn], 0,0,0);
        O[1][fn] = __builtin_amdgcn_mfma_f32_16x16x32_bf16(pf[1][kk], vf, O[1][fn], 0,0,0);
      }
    __syncthreads();
  }
  #pragma unroll
  for (int fm = 0; fm < 2; fm++)
    #pragma unroll
    for (int r = 0; r < 4; r++){
      float inv = __builtin_amdgcn_rcpf(lrow[fm][r]);
      int qrow = q0 + fm*16 + lg*4 + r;
      #pragma unroll
      for (int fn = 0; fn < 4; fn++)
        Og[((size_t)b*512 + qrow)*768 + h*64 + fn*16 + l15] = f2bf(O[fm][fn][r] * inv);
    }
}

// ---------------------------------------------------------------------------
extern "C" void kernel_launch(void* const* d_in, const int* in_sizes, int n_in,
                              void* d_out, int out_size, void* d_ws, size_t ws_size,
                              hipStream_t stream){
  const float* x   = (const float*)d_in[0];
  const float* sp  = (const float*)d_in[1];
  const float* ed  = (const float*)d_in[2];
  const float* Wq  = (const float*)d_in[3];
  const float* Wk  = (const float*)d_in[4];
  const float* Wv  = (const float*)d_in[5];
  const float* bv  = (const float*)d_in[6];
  const float* Wo  = (const float*)d_in[7];
  const float* bo  = (const float*)d_in[8];
  const float* g1  = (const float*)d_in[9];
  const float* be1 = (const float*)d_in[10];
  const float* g2  = (const float*)d_in[11];
  const float* be2 = (const float*)d_in[12];
  const float* W1  = (const float*)d_in[13];
  const float* bf1 = (const float*)d_in[14];
  const float* W2  = (const float*)d_in[15];
  const float* bf2 = (const float*)d_in[16];

  char* w = (char*)d_ws;
  size_t off = 0;
  auto alloc = [&](size_t bytes)->void*{ void* p = w + off; off += (bytes + 255) & ~(size_t)255; return p; };
  u16*   Gg    = (u16*)  alloc(8192ull*3072*2);   // FFN1 out; first 37.7MB double as qkv
  u16*   qkv   = Gg;                               // [8192][2304] bf16 (dead before FFN1)
  u16*   VTg   = (u16*)  alloc(8192ull*768*2);
  u16*   hn    = (u16*)  alloc(8192ull*768*2);    // shared LN core (g/b folded into W)
  u16*   Og    = (u16*)  alloc(8192ull*768*2);
  u16*   attb  = (u16*)  alloc(8192ull*768*2);    // bf16 att residual
  u16*   biasPb= (u16*)  alloc(16ull*512*512*2);
  u16*   WqkvT = (u16*)  alloc(2304ull*768*2);
  u16*   WoT   = (u16*)  alloc(768ull*768*2);
  u16*   W1T   = (u16*)  alloc(3072ull*768*2);
  u16*   W2T   = (u16*)  alloc(768ull*3072*2);
  float* qkvb  = (float*)alloc(2304ull*4);
  float* bf1f  = (float*)alloc(3072ull*4);

  const float qscale = 0.03608439182435161f * LOG2E;  // D^-0.5 * log2e folded into Wq

  // --- prep ---
  prep_weights<<<6912, dim3(32,8), 0, stream>>>(Wq, Wk, Wv, Wo, W1, W2, g1, g2,
                                                WqkvT, WoT, W1T, W2T, qscale);
  fold_bias<<<84, 256, 0, stream>>>(Wq, Wk, Wv, W1, be1, be2, bv, bf1, qkvb, bf1f);
  bias_prep<<<4096, 256, 0, stream>>>(biasPb, sp, ed);

  // --- layer norm core (single tensor, g/b folded) ---
  ln_kernel<<<2048, 256, 0, stream>>>(x, hn);

  // --- qkv projection with fused V-transpose (EPI 5) ---
  gemm_bt<5><<<dim3(18,64),256,0,stream>>>(hn, WqkvT, qkv, qkvb, nullptr, VTg, 8192, 2304, 768);

  // --- attention ---
  attn_kernel<<<dim3(4,192),256,0,stream>>>(qkv, VTg, biasPb, Og);

  // --- output projection + residual x -> bf16 att ---
  gemm_bt<3><<<dim3(6,64),256,0,stream>>>(Og, WoT, attb, bo, x, nullptr, 8192, 768, 768);

  // --- FFN ---
  gemm_bt<2><<<dim3(24,64),256,0,stream>>>(hn, W1T, Gg, bf1f, nullptr, nullptr, 8192, 3072, 768);
  gemm_bt<4><<<dim3(6,64),256,0,stream>>>(Gg, W2T, (float*)d_out, bf2, attb, nullptr, 8192, 768, 3072);
}

// Round 13
// 255.340 us; speedup vs baseline: 1.1514x; 1.0057x over previous
//
#include <hip/hip_runtime.h>
#include <math.h>

typedef unsigned short u16;
typedef __bf16 bf16x8 __attribute__((ext_vector_type(8)));
typedef float f32x4 __attribute__((ext_vector_type(4)));

__device__ __forceinline__ u16 f2bf(float f){
  union{float f; unsigned u;} v; v.f = f;
  return (u16)((v.u + 0x7fffu + ((v.u >> 16) & 1u)) >> 16);
}
__device__ __forceinline__ float bf2f(u16 b){
  union{unsigned u; float f;} v; v.u = (unsigned)b << 16; return v.f;
}

#define LOG2E 1.4426950408889634f

// ---------------------------------------------------------------------------
// One kernel for all 6 weight transposes: fp32 [R][C] -> bf16 [C][R],
// optionally row-scaled (rs[k], k = source row) and const-scaled.
__global__ void prep_weights(const float* __restrict__ Wq, const float* __restrict__ Wk,
                             const float* __restrict__ Wv, const float* __restrict__ Wo,
                             const float* __restrict__ W1, const float* __restrict__ W2,
                             const float* __restrict__ g1, const float* __restrict__ g2,
                             u16* __restrict__ WqkvT, u16* __restrict__ WoT,
                             u16* __restrict__ W1T, u16* __restrict__ W2T, float qscale){
  __shared__ float t[32][33];
  int bid = blockIdx.x;
  const float* src; u16* dst; const float* rs; float sc; int R, C, bx, by;
  if (bid < 576)      {            src=Wq; dst=WqkvT;          rs=g1;      sc=qscale; R=768;  C=768;  bx=bid%24; by=bid/24; }
  else if (bid <1152) { bid-=576;  src=Wk; dst=WqkvT+768*768;  rs=g1;      sc=1.f;    R=768;  C=768;  bx=bid%24; by=bid/24; }
  else if (bid <1728) { bid-=1152; src=Wv; dst=WqkvT+1536*768; rs=g1;      sc=1.f;    R=768;  C=768;  bx=bid%24; by=bid/24; }
  else if (bid <2304) { bid-=1728; src=Wo; dst=WoT;            rs=nullptr; sc=1.f;    R=768;  C=768;  bx=bid%24; by=bid/24; }
  else if (bid <4608) { bid-=2304; src=W1; dst=W1T;            rs=g2;      sc=1.f;    R=768;  C=3072; bx=bid%96; by=bid/96; }
  else                { bid-=4608; src=W2; dst=W2T;            rs=nullptr; sc=1.f;    R=3072; C=768;  bx=bid%24; by=bid/24; }
  int c0 = bx * 32, r0 = by * 32;
  int tx = threadIdx.x, ty = threadIdx.y;
  #pragma unroll
  for (int i = 0; i < 4; i++)
    t[ty + i*8][tx] = src[(size_t)(r0 + ty + i*8) * C + c0 + tx];
  __syncthreads();
  float fac = (rs ? rs[r0 + tx] : 1.f) * sc;   // k-index at write = r0+tx
  #pragma unroll
  for (int i = 0; i < 4; i++)
    dst[(size_t)(c0 + ty + i*8) * R + r0 + tx] = f2bf(t[tx][ty + i*8] * fac);
}

// ---------------------------------------------------------------------------
// Parallel bias folding (two GEMVs). Block = 64 cols x 4 k-groups; coalesced.
__global__ __launch_bounds__(256) void fold_bias(
    const float* __restrict__ Wq, const float* __restrict__ Wk,
    const float* __restrict__ Wv, const float* __restrict__ W1,
    const float* __restrict__ be1, const float* __restrict__ be2,
    const float* __restrict__ bv, const float* __restrict__ bf1,
    float* __restrict__ qkvb, float* __restrict__ bf1f){
  __shared__ float red[4][64];
  int tx = threadIdx.x & 63, ty = threadIdx.x >> 6;
  int j = blockIdx.x * 64 + tx;                  // 0..5375 (grid 84, uniform per block)
  const float* W; int col, stride; const float* bvec;
  if (j < 768)       { W = Wq; col = j;        stride = 768;  bvec = be1; }
  else if (j < 1536) { W = Wk; col = j - 768;  stride = 768;  bvec = be1; }
  else if (j < 2304) { W = Wv; col = j - 1536; stride = 768;  bvec = be1; }
  else               { W = W1; col = j - 2304; stride = 3072; bvec = be2; }
  float s = 0.f;
  for (int k = ty * 192; k < (ty + 1) * 192; k++)
    s += bvec[k] * W[(size_t)k * stride + col];
  red[ty][tx] = s;
  __syncthreads();
  if (ty == 0){
    s = red[0][tx] + red[1][tx] + red[2][tx] + red[3][tx];
    if (j < 1536)      qkvb[j] = s;
    else if (j < 2304) qkvb[j] = s + bv[col];
    else               bf1f[col] = s + bf1[col];
  }
}

// biasPb[b][q][kt][l15][fk] = bf16( (sp+ed)[b][q][kt*128 + fk*16 + l15] * log2e )
__global__ void bias_prep(u16* __restrict__ dst, const float* __restrict__ sp,
                          const float* __restrict__ ed){
  int t = blockIdx.x * blockDim.x + threadIdx.x;   // 16*512*128
  int row = t >> 7, c0 = (t & 127) * 4;
  size_t base = (size_t)row * 512;
  float4 s = *(const float4*)&sp[base + c0];
  float4 e = *(const float4*)&ed[base + c0];
  int kt = c0 >> 7, cw = c0 & 127, fk = cw >> 4, l0 = cw & 15;
  u16* o = dst + base + kt*128 + fk;
  o[(l0+0)*8] = f2bf((s.x+e.x)*LOG2E);
  o[(l0+1)*8] = f2bf((s.y+e.y)*LOG2E);
  o[(l0+2)*8] = f2bf((s.z+e.z)*LOG2E);
  o[(l0+3)*8] = f2bf((s.w+e.w)*LOG2E);
}

// ---------------------------------------------------------------------------
// LayerNorm core only: hn = (x - mu) * rsqrt(var + eps)   (g/b folded into W)
__global__ __launch_bounds__(256) void ln_kernel(
    const float* __restrict__ x, u16* __restrict__ hn){
  const int lane = threadIdx.x & 63, wave = threadIdx.x >> 6;
  const int row = blockIdx.x * 4 + wave;
  const float4* xr = (const float4*)(x + (size_t)row * 768);
  float4 v[3];
  float sum = 0.f, sq = 0.f;
  #pragma unroll
  for (int c = 0; c < 3; c++){
    v[c] = xr[lane + 64*c];
    sum += v[c].x + v[c].y + v[c].z + v[c].w;
    sq  += v[c].x*v[c].x + v[c].y*v[c].y + v[c].z*v[c].z + v[c].w*v[c].w;
  }
  #pragma unroll
  for (int d = 1; d < 64; d <<= 1){ sum += __shfl_xor(sum, d); sq += __shfl_xor(sq, d); }
  float mu  = sum * (1.f/768.f);
  float var = sq * (1.f/768.f) - mu*mu;
  float rs  = rsqrtf(var + 1e-5f);
  #pragma unroll
  for (int c = 0; c < 3; c++){
    int f4 = lane + 64*c;
    ushort4 o{f2bf((v[c].x-mu)*rs), f2bf((v[c].y-mu)*rs),
              f2bf((v[c].z-mu)*rs), f2bf((v[c].w-mu)*rs)};
    ((ushort4*)(hn + (size_t)row*768))[f4] = o;
  }
}

// ---------------------------------------------------------------------------
// GEMM: C[M,N] = A[M,K](bf16) @ Bt[N,K](bf16)^T, fp32 accum.  Proven R4
// structure: 128x128 tile, 64x64/wave, BK=64, XOR-swizzled single-buffer LDS,
// XCD-aware block swizzle, 2 barriers per K-step.
// EPI 0: +bias -> bf16            EPI 2: +bias, gelu -> bf16
// EPI 3: +bias +resid(f32) -> bf16   EPI 4: +bias +resid(bf16) -> f32
// EPI 5: qkv fused epilogue — cols<1536 row-major bf16; cols>=1536 write
//        V directly into the swizzled VT[bh][hd][n'] layout (vtrans fused).
template<int EPI>
__global__ __launch_bounds__(256, 2) void gemm_bt(
    const u16* __restrict__ A, const u16* __restrict__ Bt, void* __restrict__ Cout,
    const float* __restrict__ bias, const void* __restrict__ resid,
    u16* __restrict__ vt, int M, int Nn, int K){
  __shared__ __align__(16) u16 As[128*64];
  __shared__ __align__(16) u16 Bs[128*64];
  const int tid = threadIdx.x, lane = tid & 63, wave = tid >> 6;
  const int wm = wave >> 1, wn = wave & 1;
  const int l15 = lane & 15, lg = lane >> 4;
  const int bid = blockIdx.y * gridDim.x + blockIdx.x;
  const int cpx = (gridDim.x * gridDim.y) >> 3;
  const int swz = (bid & 7) * cpx + (bid >> 3);
  const int m0 = (swz / gridDim.x) * 128, n0 = (swz % gridDim.x) * 128;
  f32x4 acc[4][4] = {};
  for (int k0 = 0; k0 < K; k0 += 64){
    #pragma unroll
    for (int i = 0; i < 4; i++){
      int chunk = i*256 + tid;
      int row = chunk >> 3, seg = (chunk & 7) ^ (row & 7);
      __builtin_amdgcn_global_load_lds(
        (const __attribute__((address_space(1))) void*)&A[(size_t)(m0+row)*K + k0 + seg*8],
        (__attribute__((address_space(3))) void*)&As[(size_t)(i*256 + wave*64)*8], 16, 0, 0);
      __builtin_amdgcn_global_load_lds(
        (const __attribute__((address_space(1))) void*)&Bt[(size_t)(n0+row)*K + k0 + seg*8],
        (__attribute__((address_space(3))) void*)&Bs[(size_t)(i*256 + wave*64)*8], 16, 0, 0);
    }
    __syncthreads();
    bf16x8 af[4][2], bfr[4][2];
    #pragma unroll
    for (int i = 0; i < 4; i++){
      int ra = wm*64 + i*16 + l15, rb = wn*64 + i*16 + l15;
      #pragma unroll
      for (int kk = 0; kk < 2; kk++){
        af[i][kk]  = *(const bf16x8*)&As[ra*64 + (((kk*4 + lg) ^ (l15 & 7)) << 3)];
        bfr[i][kk] = *(const bf16x8*)&Bs[rb*64 + (((kk*4 + lg) ^ (l15 & 7)) << 3)];
      }
    }
    #pragma unroll
    for (int kk = 0; kk < 2; kk++)
      #pragma unroll
      for (int i = 0; i < 4; i++)
        #pragma unroll
        for (int j = 0; j < 4; j++)
          acc[i][j] = __builtin_amdgcn_mfma_f32_16x16x32_bf16(af[i][kk], bfr[j][kk], acc[i][j], 0, 0, 0);
    __syncthreads();
  }
  #pragma unroll
  for (int i = 0; i < 4; i++){
    int row_base = m0 + wm*64 + i*16 + lg*4;
    #pragma unroll
    for (int j = 0; j < 4; j++){
      int col = n0 + wn*64 + j*16 + l15;
      float bcol = bias ? bias[col] : 0.f;
      if (EPI == 5 && col >= 1536){
        int hv = (col - 1536) >> 6, hd = (col - 1536) & 63;
        int b = row_base >> 9, n = row_base & 511;
        int within = n & 127;
        int newn = (n & ~127) + ((((within >> 3) ^ (hd & 7)) << 3)) + (within & 7);
        ushort4 ov{f2bf(acc[i][j][0] + bcol), f2bf(acc[i][j][1] + bcol),
                   f2bf(acc[i][j][2] + bcol), f2bf(acc[i][j][3] + bcol)};
        *(ushort4*)&vt[(((size_t)(b*12 + hv)*64 + hd) << 9) + newn] = ov;
        continue;
      }
      #pragma unroll
      for (int r = 0; r < 4; r++){
        size_t idx = (size_t)(row_base + r) * Nn + col;
        float v = acc[i][j][r] + bcol;
        if (EPI == 3){
          v += ((const float*)resid)[idx];
          ((u16*)Cout)[idx] = f2bf(v);
        } else if (EPI == 4){
          v += bf2f(((const u16*)resid)[idx]);
          ((float*)Cout)[idx] = v;
        } else if (EPI == 2){
          float u = v + 0.044715f * v * v * v;
          float e = exp2f(-2.3022182f * u);          // exp(-1.5957691*u)
          ((u16*)Cout)[idx] = f2bf(v * __builtin_amdgcn_rcpf(1.f + e));
        } else {
          ((u16*)Cout)[idx] = f2bf(v);               // EPI 0 and EPI 5 (Q/K part)
        }
      }
    }
  }
}

// ---------------------------------------------------------------------------
// Attention body (per-block): q-tile 128 x (b,h); 4 waves, each 32 q-rows.
__device__ __forceinline__ void attn_body(
    int bid, u16* sm, const u16* __restrict__ qkv, const u16* __restrict__ VTg,
    const u16* __restrict__ biasPb, u16* __restrict__ Og){
  u16* Ks = sm;               // [128*64]
  u16* Vs = sm + 8192;        // [64*128]
  u16* Pl = sm + 16384;       // [4*32*136]
  const int tid = threadIdx.x, lane = tid & 63, wave = tid >> 6;
  const int l15 = lane & 15, lg = lane >> 4;
  const int swz = (bid & 7) * 96 + (bid >> 3);     // nwg = 768
  const int bh = swz >> 2, b = bh / 12, h = bh % 12;
  const int q0 = (swz & 3) * 128 + wave * 32;
  const u16* Qb = qkv + (size_t)b * 512 * 2304 + h * 64;   // row stride 2304
  const u16* Kb = Qb + 768;
  const u16* Vbh = VTg + (size_t)bh * 64 * 512;
  u16* Pw = &Pl[wave * 32 * 136];

  bf16x8 qf[2][2];
  #pragma unroll
  for (int fm = 0; fm < 2; fm++)
    #pragma unroll
    for (int kk = 0; kk < 2; kk++)
      qf[fm][kk] = *(const bf16x8*)&Qb[(size_t)(q0 + fm*16 + l15)*2304 + kk*32 + lg*8];

  f32x4 O[2][4] = {};
  float lrow[2][4] = {};

  for (int kt = 0; kt < 4; kt++){
    const int k0 = kt * 128;
    bf16x8 bb[2][4];
    #pragma unroll
    for (int fm = 0; fm < 2; fm++)
      #pragma unroll
      for (int r = 0; r < 4; r++){
        int qrow = q0 + fm*16 + lg*4 + r;
        bb[fm][r] = *(const bf16x8*)&biasPb[((size_t)(b*512 + qrow)*4 + kt)*128 + l15*8];
      }
    #pragma unroll
    for (int i = 0; i < 4; i++){
      int chunk = i*256 + tid;
      int r = chunk >> 3, cc = chunk & 7;
      __builtin_amdgcn_global_load_lds(
        (const __attribute__((address_space(1))) void*)&Kb[(size_t)(k0 + r)*2304 + ((cc ^ (r & 7)) << 3)],
        (__attribute__((address_space(3))) void*)&Ks[(size_t)(i*256 + wave*64)*8],
        16, 0, 0);
    }
    #pragma unroll
    for (int i = 0; i < 4; i++){
      int chunk = i*256 + tid;
      int r = chunk >> 4, cc = chunk & 15;
      __builtin_amdgcn_global_load_lds(
        (const __attribute__((address_space(1))) void*)&Vbh[(size_t)r*512 + k0 + (cc << 3)],
        (__attribute__((address_space(3))) void*)&Vs[(size_t)(i*256 + wave*64)*8],
        16, 0, 0);
    }
    __syncthreads();

    f32x4 S[2][8] = {};
    #pragma unroll
    for (int fk = 0; fk < 8; fk++)
      #pragma unroll
      for (int kk = 0; kk < 2; kk++){
        int row = fk*16 + l15;
        bf16x8 kf = *(const bf16x8*)&Ks[row*64 + (((kk*4 + lg) ^ (l15 & 7)) << 3)];
        S[0][fk] = __builtin_amdgcn_mfma_f32_16x16x32_bf16(qf[0][kk], kf, S[0][fk], 0,0,0);
        S[1][fk] = __builtin_amdgcn_mfma_f32_16x16x32_bf16(qf[1][kk], kf, S[1][fk], 0,0,0);
      }
    #pragma unroll
    for (int fm = 0; fm < 2; fm++)
      #pragma unroll
      for (int r = 0; r < 4; r++){
        float rs = 0.f;
        #pragma unroll
        for (int fk = 0; fk < 8; fk++){
          float p = exp2f(S[fm][fk][r] + (float)bb[fm][r][fk]);
          S[fm][fk][r] = p;
          rs += p;
        }
        rs += __shfl_xor(rs, 1); rs += __shfl_xor(rs, 2);
        rs += __shfl_xor(rs, 4); rs += __shfl_xor(rs, 8);
        lrow[fm][r] += rs;
      }
    #pragma unroll
    for (int fm = 0; fm < 2; fm++)
      #pragma unroll
      for (int fk = 0; fk < 8; fk++)
        #pragma unroll
        for (int r = 0; r < 4; r++)
          Pw[(fm*16 + lg*4 + r)*136 + fk*16 + l15] = f2bf(S[fm][fk][r]);
    bf16x8 pf[2][4];
    #pragma unroll
    for (int fm = 0; fm < 2; fm++)
      #pragma unroll
      for (int kk = 0; kk < 4; kk++)
        pf[fm][kk] = *(const bf16x8*)&Pw[(fm*16 + l15)*136 + kk*32 + lg*8];
    #pragma unroll
    for (int fn = 0; fn < 4; fn++)
      #pragma unroll
      for (int kk = 0; kk < 4; kk++){
        int row = fn*16 + l15;
        bf16x8 vf = *(const bf16x8*)&Vs[row*128 + (((kk*4 + lg) ^ (l15 & 7)) << 3)];
        O[0][fn] = __builtin_amdgcn_mfma_f32_16x16x32_bf16(pf[0][kk], vf, O[0][fn], 0,0,0);
        O[1][fn] = __builtin_amdgcn_mfma_f32_16x16x32_bf16(pf[1][kk], vf, O[1][fn], 0,0,0);
      }
    __syncthreads();
  }
  #pragma unroll
  for (int fm = 0; fm < 2; fm++)
    #pragma unroll
    for (int r = 0; r < 4; r++){
      float inv = __builtin_amdgcn_rcpf(lrow[fm][r]);
      int qrow = q0 + fm*16 + lg*4 + r;
      #pragma unroll
      for (int fn = 0; fn < 4; fn++)
        Og[((size_t)b*512 + qrow)*768 + h*64 + fn*16 + l15] = f2bf(O[fm][fn][r] * inv);
    }
}

// ---------------------------------------------------------------------------
// FFN1 body (per-block): gemm 128x128 tile, EPI2 (gelu), M=8192 N=3072 K=768.
__device__ __forceinline__ void ffn1_body(
    int fid, u16* sm, const u16* __restrict__ A, const u16* __restrict__ Bt,
    u16* __restrict__ Cout, const float* __restrict__ bias){
  u16* As = sm;               // [128*64]
  u16* Bs = sm + 8192;        // [128*64]
  const int Nn = 3072, K = 768;
  const int tid = threadIdx.x, lane = tid & 63, wave = tid >> 6;
  const int wm = wave >> 1, wn = wave & 1;
  const int l15 = lane & 15, lg = lane >> 4;
  const int swz = (fid & 7) * 192 + (fid >> 3);    // nwg = 1536 (24 x 64)
  const int m0 = (swz / 24) * 128, n0 = (swz % 24) * 128;
  f32x4 acc[4][4] = {};
  for (int k0 = 0; k0 < K; k0 += 64){
    #pragma unroll
    for (int i = 0; i < 4; i++){
      int chunk = i*256 + tid;
      int row = chunk >> 3, seg = (chunk & 7) ^ (row & 7);
      __builtin_amdgcn_global_load_lds(
        (const __attribute__((address_space(1))) void*)&A[(size_t)(m0+row)*K + k0 + seg*8],
        (__attribute__((address_space(3))) void*)&As[(size_t)(i*256 + wave*64)*8], 16, 0, 0);
      __builtin_amdgcn_global_load_lds(
        (const __attribute__((address_space(1))) void*)&Bt[(size_t)(n0+row)*K + k0 + seg*8],
        (__attribute__((address_space(3))) void*)&Bs[(size_t)(i*256 + wave*64)*8], 16, 0, 0);
    }
    __syncthreads();
    bf16x8 af[4][2], bfr[4][2];
    #pragma unroll
    for (int i = 0; i < 4; i++){
      int ra = wm*64 + i*16 + l15, rb = wn*64 + i*16 + l15;
      #pragma unroll
      for (int kk = 0; kk < 2; kk++){
        af[i][kk]  = *(const bf16x8*)&As[ra*64 + (((kk*4 + lg) ^ (l15 & 7)) << 3)];
        bfr[i][kk] = *(const bf16x8*)&Bs[rb*64 + (((kk*4 + lg) ^ (l15 & 7)) << 3)];
      }
    }
    #pragma unroll
    for (int kk = 0; kk < 2; kk++)
      #pragma unroll
      for (int i = 0; i < 4; i++)
        #pragma unroll
        for (int j = 0; j < 4; j++)
          acc[i][j] = __builtin_amdgcn_mfma_f32_16x16x32_bf16(af[i][kk], bfr[j][kk], acc[i][j], 0, 0, 0);
    __syncthreads();
  }
  #pragma unroll
  for (int i = 0; i < 4; i++){
    int row_base = m0 + wm*64 + i*16 + lg*4;
    #pragma unroll
    for (int j = 0; j < 4; j++){
      int col = n0 + wn*64 + j*16 + l15;
      float bcol = bias[col];
      #pragma unroll
      for (int r = 0; r < 4; r++){
        size_t idx = (size_t)(row_base + r) * Nn + col;
        float v = acc[i][j][r] + bcol;
        float u = v + 0.044715f * v * v * v;
        float e = exp2f(-2.3022182f * u);            // exp(-1.5957691*u)
        Cout[idx] = f2bf(v * __builtin_amdgcn_rcpf(1.f + e));
      }
    }
  }
}

// ---------------------------------------------------------------------------
// Fused attention + FFN1: independent work co-scheduled on the CUs.
// Grid 2304: bid%3==0 -> attn block (768), else -> FFN1 block (1536).
__global__ __launch_bounds__(256, 2) void attn_ffn1(
    const u16* __restrict__ qkv, const u16* __restrict__ VTg,
    const u16* __restrict__ biasPb, u16* __restrict__ Og,
    const u16* __restrict__ hn, const u16* __restrict__ W1T,
    u16* __restrict__ Gg, const float* __restrict__ bf1f){
  __shared__ __align__(16) u16 sm[33792];   // attn: 66 KB; gemm uses first 32 KB
  const int bid = blockIdx.x;
  const int t = bid / 3, r = bid - t * 3;
  if (r == 0) attn_body(t, sm, qkv, VTg, biasPb, Og);
  else        ffn1_body(2*t + (r-1), sm, hn, W1T, Gg, bf1f);
}

// ---------------------------------------------------------------------------
extern "C" void kernel_launch(void* const* d_in, const int* in_sizes, int n_in,
                              void* d_out, int out_size, void* d_ws, size_t ws_size,
                              hipStream_t stream){
  const float* x   = (const float*)d_in[0];
  const float* sp  = (const float*)d_in[1];
  const float* ed  = (const float*)d_in[2];
  const float* Wq  = (const float*)d_in[3];
  const float* Wk  = (const float*)d_in[4];
  const float* Wv  = (const float*)d_in[5];
  const float* bv  = (const float*)d_in[6];
  const float* Wo  = (const float*)d_in[7];
  const float* bo  = (const float*)d_in[8];
  const float* g1  = (const float*)d_in[9];
  const float* be1 = (const float*)d_in[10];
  const float* g2  = (const float*)d_in[11];
  const float* be2 = (const float*)d_in[12];
  const float* W1  = (const float*)d_in[13];
  const float* bf1 = (const float*)d_in[14];
  const float* W2  = (const float*)d_in[15];
  const float* bf2 = (const float*)d_in[16];

  char* w = (char*)d_ws;
  size_t off = 0;
  auto alloc = [&](size_t bytes)->void*{ void* p = w + off; off += (bytes + 255) & ~(size_t)255; return p; };
  u16*   Gg    = (u16*)  alloc(8192ull*3072*2);   // 50.3 MB (own region: FFN1 runs during attn)
  u16*   qkv   = (u16*)  alloc(8192ull*2304*2);   // 37.7 MB
  u16*   attb  = qkv;                              // overlay: qkv dead before o-proj writes attb
  u16*   VTg   = (u16*)  alloc(8192ull*768*2);
  u16*   hn    = (u16*)  alloc(8192ull*768*2);    // shared LN core (g/b folded into W)
  u16*   Og    = (u16*)  alloc(8192ull*768*2);
  u16*   biasPb= (u16*)  alloc(16ull*512*512*2);
  u16*   WqkvT = (u16*)  alloc(2304ull*768*2);
  u16*   WoT   = (u16*)  alloc(768ull*768*2);
  u16*   W1T   = (u16*)  alloc(3072ull*768*2);
  u16*   W2T   = (u16*)  alloc(768ull*3072*2);
  float* qkvb  = (float*)alloc(2304ull*4);
  float* bf1f  = (float*)alloc(3072ull*4);

  const float qscale = 0.03608439182435161f * LOG2E;  // D^-0.5 * log2e folded into Wq

  // --- prep ---
  prep_weights<<<6912, dim3(32,8), 0, stream>>>(Wq, Wk, Wv, Wo, W1, W2, g1, g2,
                                                WqkvT, WoT, W1T, W2T, qscale);
  fold_bias<<<84, 256, 0, stream>>>(Wq, Wk, Wv, W1, be1, be2, bv, bf1, qkvb, bf1f);
  bias_prep<<<4096, 256, 0, stream>>>(biasPb, sp, ed);

  // --- layer norm core (single tensor, g/b folded) ---
  ln_kernel<<<2048, 256, 0, stream>>>(x, hn);

  // --- qkv projection with fused V-transpose (EPI 5) ---
  gemm_bt<5><<<dim3(18,64),256,0,stream>>>(hn, WqkvT, qkv, qkvb, nullptr, VTg, 8192, 2304, 768);

  // --- attention + FFN1 fused (independent work, co-scheduled) ---
  attn_ffn1<<<2304, 256, 0, stream>>>(qkv, VTg, biasPb, Og, hn, W1T, Gg, bf1f);

  // --- output projection + residual x -> bf16 att (attb overlays dead qkv) ---
  gemm_bt<3><<<dim3(6,64),256,0,stream>>>(Og, WoT, attb, bo, x, nullptr, 8192, 768, 768);

  // --- FFN2 ---
  gemm_bt<4><<<dim3(6,64),256,0,stream>>>(Gg, W2T, (float*)d_out, bf2, attb, nullptr, 8192, 768, 3072);
}

// Round 14
// 234.932 us; speedup vs baseline: 1.2514x; 1.0869x over previous
//
#include <hip/hip_runtime.h>
#include <math.h>

typedef unsigned short u16;
typedef __bf16 bf16x8 __attribute__((ext_vector_type(8)));
typedef float f32x4 __attribute__((ext_vector_type(4)));

__device__ __forceinline__ u16 f2bf(float f){
  union{float f; unsigned u;} v; v.f = f;
  return (u16)((v.u + 0x7fffu + ((v.u >> 16) & 1u)) >> 16);
}

#define LOG2E 1.4426950408889634f

// ---------------------------------------------------------------------------
// Mega-prep: one dispatch, four independent jobs branch on blockIdx.
//  [0,4096)        bias_prep   biasPb[b][q][kt][l15][fk] = bf16((sp+ed)*log2e)
//  [4096,11008)    prep_weights 6 transposes fp32->bf16 (g1/g2/qscale folded)
//  [11008,11104)   fold_bias   qkvb / bf1f GEMVs + bo2 = bo + bf2
//  [11104,13152)   ln          hn = (x-mu)*rsqrt(var+eps)
__global__ __launch_bounds__(256) void prep_all(
    const float* __restrict__ sp, const float* __restrict__ ed,
    const float* __restrict__ Wq, const float* __restrict__ Wk,
    const float* __restrict__ Wv, const float* __restrict__ Wo,
    const float* __restrict__ W1, const float* __restrict__ W2,
    const float* __restrict__ g1, const float* __restrict__ g2,
    const float* __restrict__ be1, const float* __restrict__ be2,
    const float* __restrict__ bv, const float* __restrict__ bf1,
    const float* __restrict__ bo, const float* __restrict__ bf2,
    const float* __restrict__ x,
    u16* __restrict__ biasPb, u16* __restrict__ WqkvT, u16* __restrict__ WoT,
    u16* __restrict__ W1T, u16* __restrict__ W2T,
    float* __restrict__ qkvb, float* __restrict__ bf1f, float* __restrict__ bo2,
    u16* __restrict__ hn, float qscale){
  __shared__ float t[32][33];
  __shared__ float red[4][64];
  const int gbid = blockIdx.x, tid = threadIdx.x;

  if (gbid < 4096){
    // ---- bias_prep ----
    int tt = gbid * 256 + tid;
    int row = tt >> 7, c0 = (tt & 127) * 4;
    size_t base = (size_t)row * 512;
    float4 s = *(const float4*)&sp[base + c0];
    float4 e = *(const float4*)&ed[base + c0];
    int kt = c0 >> 7, cw = c0 & 127, fk = cw >> 4, l0 = cw & 15;
    u16* o = biasPb + base + kt*128 + fk;
    o[(l0+0)*8] = f2bf((s.x+e.x)*LOG2E);
    o[(l0+1)*8] = f2bf((s.y+e.y)*LOG2E);
    o[(l0+2)*8] = f2bf((s.z+e.z)*LOG2E);
    o[(l0+3)*8] = f2bf((s.w+e.w)*LOG2E);
  } else if (gbid < 11008){
    // ---- prep_weights ----
    int bid = gbid - 4096;
    const float* src; u16* dst; const float* rs; float sc; int R, C, bx, by;
    if (bid < 576)      {            src=Wq; dst=WqkvT;          rs=g1;      sc=qscale; R=768;  C=768;  bx=bid%24; by=bid/24; }
    else if (bid <1152) { bid-=576;  src=Wk; dst=WqkvT+768*768;  rs=g1;      sc=1.f;    R=768;  C=768;  bx=bid%24; by=bid/24; }
    else if (bid <1728) { bid-=1152; src=Wv; dst=WqkvT+1536*768; rs=g1;      sc=1.f;    R=768;  C=768;  bx=bid%24; by=bid/24; }
    else if (bid <2304) { bid-=1728; src=Wo; dst=WoT;            rs=nullptr; sc=1.f;    R=768;  C=768;  bx=bid%24; by=bid/24; }
    else if (bid <4608) { bid-=2304; src=W1; dst=W1T;            rs=g2;      sc=1.f;    R=768;  C=3072; bx=bid%96; by=bid/96; }
    else                { bid-=4608; src=W2; dst=W2T;            rs=nullptr; sc=1.f;    R=3072; C=768;  bx=bid%24; by=bid/24; }
    int c0 = bx * 32, r0 = by * 32;
    int tx = tid & 31, ty = tid >> 5;
    #pragma unroll
    for (int i = 0; i < 4; i++)
      t[ty + i*8][tx] = src[(size_t)(r0 + ty + i*8) * C + c0 + tx];
    __syncthreads();
    float fac = (rs ? rs[r0 + tx] : 1.f) * sc;
    #pragma unroll
    for (int i = 0; i < 4; i++)
      dst[(size_t)(c0 + ty + i*8) * R + r0 + tx] = f2bf(t[tx][ty + i*8] * fac);
  } else if (gbid < 11104){
    // ---- fold_bias ----
    int fbid = gbid - 11008;
    int tx = tid & 63, ty = tid >> 6;
    int j = fbid * 64 + tx;                  // 0..6143
    if (j < 5376){
      const float* W; int col, stride; const float* bvec;
      if (j < 768)       { W = Wq; col = j;        stride = 768;  bvec = be1; }
      else if (j < 1536) { W = Wk; col = j - 768;  stride = 768;  bvec = be1; }
      else if (j < 2304) { W = Wv; col = j - 1536; stride = 768;  bvec = be1; }
      else               { W = W1; col = j - 2304; stride = 3072; bvec = be2; }
      float s = 0.f;
      for (int k = ty * 192; k < (ty + 1) * 192; k++)
        s += bvec[k] * W[(size_t)k * stride + col];
      red[ty][tx] = s;
    }
    __syncthreads();
    if (ty == 0){
      if (j < 5376){
        float s = red[0][tx] + red[1][tx] + red[2][tx] + red[3][tx];
        if (j < 1536)      qkvb[j] = s;
        else if (j < 2304) qkvb[j] = s + bv[j - 1536];
        else               bf1f[j - 2304] = s + bf1[j - 2304];
      } else {
        int col = j - 5376;
        bo2[col] = bo[col] + bf2[col];
      }
    }
  } else {
    // ---- ln ----
    int lbid = gbid - 11104;
    const int lane = tid & 63, wave = tid >> 6;
    const int row = lbid * 4 + wave;
    const float4* xr = (const float4*)(x + (size_t)row * 768);
    float4 v[3];
    float sum = 0.f, sq = 0.f;
    #pragma unroll
    for (int c = 0; c < 3; c++){
      v[c] = xr[lane + 64*c];
      sum += v[c].x + v[c].y + v[c].z + v[c].w;
      sq  += v[c].x*v[c].x + v[c].y*v[c].y + v[c].z*v[c].z + v[c].w*v[c].w;
    }
    #pragma unroll
    for (int d = 1; d < 64; d <<= 1){ sum += __shfl_xor(sum, d); sq += __shfl_xor(sq, d); }
    float mu  = sum * (1.f/768.f);
    float var = sq * (1.f/768.f) - mu*mu;
    float rs  = rsqrtf(var + 1e-5f);
    #pragma unroll
    for (int c = 0; c < 3; c++){
      int f4 = lane + 64*c;
      ushort4 o{f2bf((v[c].x-mu)*rs), f2bf((v[c].y-mu)*rs),
                f2bf((v[c].z-mu)*rs), f2bf((v[c].w-mu)*rs)};
      ((ushort4*)(hn + (size_t)row*768))[f4] = o;
    }
  }
}

// ---------------------------------------------------------------------------
// qkv GEMM (proven R4 structure, EPI5): C[8192,2304] = hn @ WqkvT^T + qkvb.
// cols<1536 row-major bf16; cols>=1536 V written into swizzled VT layout.
__global__ __launch_bounds__(256, 2) void gemm_qkv(
    const u16* __restrict__ A, const u16* __restrict__ Bt, u16* __restrict__ Cout,
    const float* __restrict__ bias, u16* __restrict__ vt){
  const int Nn = 2304, K = 768;
  __shared__ __align__(16) u16 As[128*64];
  __shared__ __align__(16) u16 Bs[128*64];
  const int tid = threadIdx.x, lane = tid & 63, wave = tid >> 6;
  const int wm = wave >> 1, wn = wave & 1;
  const int l15 = lane & 15, lg = lane >> 4;
  const int bid = blockIdx.y * gridDim.x + blockIdx.x;
  const int cpx = (gridDim.x * gridDim.y) >> 3;
  const int swz = (bid & 7) * cpx + (bid >> 3);
  const int m0 = (swz / gridDim.x) * 128, n0 = (swz % gridDim.x) * 128;
  f32x4 acc[4][4] = {};
  for (int k0 = 0; k0 < K; k0 += 64){
    #pragma unroll
    for (int i = 0; i < 4; i++){
      int chunk = i*256 + tid;
      int row = chunk >> 3, seg = (chunk & 7) ^ (row & 7);
      __builtin_amdgcn_global_load_lds(
        (const __attribute__((address_space(1))) void*)&A[(size_t)(m0+row)*K + k0 + seg*8],
        (__attribute__((address_space(3))) void*)&As[(size_t)(i*256 + wave*64)*8], 16, 0, 0);
      __builtin_amdgcn_global_load_lds(
        (const __attribute__((address_space(1))) void*)&Bt[(size_t)(n0+row)*K + k0 + seg*8],
        (__attribute__((address_space(3))) void*)&Bs[(size_t)(i*256 + wave*64)*8], 16, 0, 0);
    }
    __syncthreads();
    bf16x8 af[4][2], bfr[4][2];
    #pragma unroll
    for (int i = 0; i < 4; i++){
      int ra = wm*64 + i*16 + l15, rb = wn*64 + i*16 + l15;
      #pragma unroll
      for (int kk = 0; kk < 2; kk++){
        af[i][kk]  = *(const bf16x8*)&As[ra*64 + (((kk*4 + lg) ^ (l15 & 7)) << 3)];
        bfr[i][kk] = *(const bf16x8*)&Bs[rb*64 + (((kk*4 + lg) ^ (l15 & 7)) << 3)];
      }
    }
    #pragma unroll
    for (int kk = 0; kk < 2; kk++)
      #pragma unroll
      for (int i = 0; i < 4; i++)
        #pragma unroll
        for (int j = 0; j < 4; j++)
          acc[i][j] = __builtin_amdgcn_mfma_f32_16x16x32_bf16(af[i][kk], bfr[j][kk], acc[i][j], 0, 0, 0);
    __syncthreads();
  }
  #pragma unroll
  for (int i = 0; i < 4; i++){
    int row_base = m0 + wm*64 + i*16 + lg*4;
    #pragma unroll
    for (int j = 0; j < 4; j++){
      int col = n0 + wn*64 + j*16 + l15;
      float bcol = bias[col];
      if (col >= 1536){
        int hv = (col - 1536) >> 6, hd = (col - 1536) & 63;
        int b = row_base >> 9, n = row_base & 511;
        int within = n & 127;
        int newn = (n & ~127) + ((((within >> 3) ^ (hd & 7)) << 3)) + (within & 7);
        ushort4 ov{f2bf(acc[i][j][0] + bcol), f2bf(acc[i][j][1] + bcol),
                   f2bf(acc[i][j][2] + bcol), f2bf(acc[i][j][3] + bcol)};
        *(ushort4*)&vt[(((size_t)(b*12 + hv)*64 + hd) << 9) + newn] = ov;
      } else {
        #pragma unroll
        for (int r = 0; r < 4; r++)
          Cout[(size_t)(row_base + r) * Nn + col] = f2bf(acc[i][j][r] + bcol);
      }
    }
  }
}

// ---------------------------------------------------------------------------
// Attention body (per-block): q-tile 128 x (b,h); 4 waves, each 32 q-rows.
__device__ __forceinline__ void attn_body(
    int bid, u16* sm, const u16* __restrict__ qkv, const u16* __restrict__ VTg,
    const u16* __restrict__ biasPb, u16* __restrict__ Og){
  u16* Ks = sm;               // [128*64]
  u16* Vs = sm + 8192;        // [64*128]
  u16* Pl = sm + 16384;       // [4*32*136]
  const int tid = threadIdx.x, lane = tid & 63, wave = tid >> 6;
  const int l15 = lane & 15, lg = lane >> 4;
  const int swz = (bid & 7) * 96 + (bid >> 3);     // nwg = 768
  const int bh = swz >> 2, b = bh / 12, h = bh % 12;
  const int q0 = (swz & 3) * 128 + wave * 32;
  const u16* Qb = qkv + (size_t)b * 512 * 2304 + h * 64;   // row stride 2304
  const u16* Kb = Qb + 768;
  const u16* Vbh = VTg + (size_t)bh * 64 * 512;
  u16* Pw = &Pl[wave * 32 * 136];

  bf16x8 qf[2][2];
  #pragma unroll
  for (int fm = 0; fm < 2; fm++)
    #pragma unroll
    for (int kk = 0; kk < 2; kk++)
      qf[fm][kk] = *(const bf16x8*)&Qb[(size_t)(q0 + fm*16 + l15)*2304 + kk*32 + lg*8];

  f32x4 O[2][4] = {};
  float lrow[2][4] = {};

  for (int kt = 0; kt < 4; kt++){
    const int k0 = kt * 128;
    bf16x8 bb[2][4];
    #pragma unroll
    for (int fm = 0; fm < 2; fm++)
      #pragma unroll
      for (int r = 0; r < 4; r++){
        int qrow = q0 + fm*16 + lg*4 + r;
        bb[fm][r] = *(const bf16x8*)&biasPb[((size_t)(b*512 + qrow)*4 + kt)*128 + l15*8];
      }
    #pragma unroll
    for (int i = 0; i < 4; i++){
      int chunk = i*256 + tid;
      int r = chunk >> 3, cc = chunk & 7;
      __builtin_amdgcn_global_load_lds(
        (const __attribute__((address_space(1))) void*)&Kb[(size_t)(k0 + r)*2304 + ((cc ^ (r & 7)) << 3)],
        (__attribute__((address_space(3))) void*)&Ks[(size_t)(i*256 + wave*64)*8],
        16, 0, 0);
    }
    #pragma unroll
    for (int i = 0; i < 4; i++){
      int chunk = i*256 + tid;
      int r = chunk >> 4, cc = chunk & 15;
      __builtin_amdgcn_global_load_lds(
        (const __attribute__((address_space(1))) void*)&Vbh[(size_t)r*512 + k0 + (cc << 3)],
        (__attribute__((address_space(3))) void*)&Vs[(size_t)(i*256 + wave*64)*8],
        16, 0, 0);
    }
    __syncthreads();

    f32x4 S[2][8] = {};
    #pragma unroll
    for (int fk = 0; fk < 8; fk++)
      #pragma unroll
      for (int kk = 0; kk < 2; kk++){
        int row = fk*16 + l15;
        bf16x8 kf = *(const bf16x8*)&Ks[row*64 + (((kk*4 + lg) ^ (l15 & 7)) << 3)];
        S[0][fk] = __builtin_amdgcn_mfma_f32_16x16x32_bf16(qf[0][kk], kf, S[0][fk], 0,0,0);
        S[1][fk] = __builtin_amdgcn_mfma_f32_16x16x32_bf16(qf[1][kk], kf, S[1][fk], 0,0,0);
      }
    #pragma unroll
    for (int fm = 0; fm < 2; fm++)
      #pragma unroll
      for (int r = 0; r < 4; r++){
        float rs = 0.f;
        #pragma unroll
        for (int fk = 0; fk < 8; fk++){
          float p = exp2f(S[fm][fk][r] + (float)bb[fm][r][fk]);
          S[fm][fk][r] = p;
          rs += p;
        }
        rs += __shfl_xor(rs, 1); rs += __shfl_xor(rs, 2);
        rs += __shfl_xor(rs, 4); rs += __shfl_xor(rs, 8);
        lrow[fm][r] += rs;
      }
    #pragma unroll
    for (int fm = 0; fm < 2; fm++)
      #pragma unroll
      for (int fk = 0; fk < 8; fk++)
        #pragma unroll
        for (int r = 0; r < 4; r++)
          Pw[(fm*16 + lg*4 + r)*136 + fk*16 + l15] = f2bf(S[fm][fk][r]);
    bf16x8 pf[2][4];
    #pragma unroll
    for (int fm = 0; fm < 2; fm++)
      #pragma unroll
      for (int kk = 0; kk < 4; kk++)
        pf[fm][kk] = *(const bf16x8*)&Pw[(fm*16 + l15)*136 + kk*32 + lg*8];
    #pragma unroll
    for (int fn = 0; fn < 4; fn++)
      #pragma unroll
      for (int kk = 0; kk < 4; kk++){
        int row = fn*16 + l15;
        bf16x8 vf = *(const bf16x8*)&Vs[row*128 + (((kk*4 + lg) ^ (l15 & 7)) << 3)];
        O[0][fn] = __builtin_amdgcn_mfma_f32_16x16x32_bf16(pf[0][kk], vf, O[0][fn], 0,0,0);
        O[1][fn] = __builtin_amdgcn_mfma_f32_16x16x32_bf16(pf[1][kk], vf, O[1][fn], 0,0,0);
      }
    __syncthreads();
  }
  #pragma unroll
  for (int fm = 0; fm < 2; fm++)
    #pragma unroll
    for (int r = 0; r < 4; r++){
      float inv = __builtin_amdgcn_rcpf(lrow[fm][r]);
      int qrow = q0 + fm*16 + lg*4 + r;
      #pragma unroll
      for (int fn = 0; fn < 4; fn++)
        Og[((size_t)b*512 + qrow)*768 + h*64 + fn*16 + l15] = f2bf(O[fm][fn][r] * inv);
    }
}

// ---------------------------------------------------------------------------
// FFN1 body (per-block): 128x128 tile, gelu epilogue. M=8192 N=3072 K=768.
__device__ __forceinline__ void ffn1_body(
    int fid, u16* sm, const u16* __restrict__ A, const u16* __restrict__ Bt,
    u16* __restrict__ Cout, const float* __restrict__ bias){
  u16* As = sm;               // [128*64]
  u16* Bs = sm + 8192;        // [128*64]
  const int Nn = 3072, K = 768;
  const int tid = threadIdx.x, lane = tid & 63, wave = tid >> 6;
  const int wm = wave >> 1, wn = wave & 1;
  const int l15 = lane & 15, lg = lane >> 4;
  const int swz = (fid & 7) * 192 + (fid >> 3);    // nwg = 1536 (24 x 64)
  const int m0 = (swz / 24) * 128, n0 = (swz % 24) * 128;
  f32x4 acc[4][4] = {};
  for (int k0 = 0; k0 < K; k0 += 64){
    #pragma unroll
    for (int i = 0; i < 4; i++){
      int chunk = i*256 + tid;
      int row = chunk >> 3, seg = (chunk & 7) ^ (row & 7);
      __builtin_amdgcn_global_load_lds(
        (const __attribute__((address_space(1))) void*)&A[(size_t)(m0+row)*K + k0 + seg*8],
        (__attribute__((address_space(3))) void*)&As[(size_t)(i*256 + wave*64)*8], 16, 0, 0);
      __builtin_amdgcn_global_load_lds(
        (const __attribute__((address_space(1))) void*)&Bt[(size_t)(n0+row)*K + k0 + seg*8],
        (__attribute__((address_space(3))) void*)&Bs[(size_t)(i*256 + wave*64)*8], 16, 0, 0);
    }
    __syncthreads();
    bf16x8 af[4][2], bfr[4][2];
    #pragma unroll
    for (int i = 0; i < 4; i++){
      int ra = wm*64 + i*16 + l15, rb = wn*64 + i*16 + l15;
      #pragma unroll
      for (int kk = 0; kk < 2; kk++){
        af[i][kk]  = *(const bf16x8*)&As[ra*64 + (((kk*4 + lg) ^ (l15 & 7)) << 3)];
        bfr[i][kk] = *(const bf16x8*)&Bs[rb*64 + (((kk*4 + lg) ^ (l15 & 7)) << 3)];
      }
    }
    #pragma unroll
    for (int kk = 0; kk < 2; kk++)
      #pragma unroll
      for (int i = 0; i < 4; i++)
        #pragma unroll
        for (int j = 0; j < 4; j++)
          acc[i][j] = __builtin_amdgcn_mfma_f32_16x16x32_bf16(af[i][kk], bfr[j][kk], acc[i][j], 0, 0, 0);
    __syncthreads();
  }
  #pragma unroll
  for (int i = 0; i < 4; i++){
    int row_base = m0 + wm*64 + i*16 + lg*4;
    #pragma unroll
    for (int j = 0; j < 4; j++){
      int col = n0 + wn*64 + j*16 + l15;
      float bcol = bias[col];
      #pragma unroll
      for (int r = 0; r < 4; r++){
        size_t idx = (size_t)(row_base + r) * Nn + col;
        float v = acc[i][j][r] + bcol;
        float u = v + 0.044715f * v * v * v;
        float e = exp2f(-2.3022182f * u);            // exp(-1.5957691*u)
        Cout[idx] = f2bf(v * __builtin_amdgcn_rcpf(1.f + e));
      }
    }
  }
}

// ---------------------------------------------------------------------------
// Fused attention + FFN1 (independent work co-scheduled).
// Grid 2304: bid%3==0 -> attn (768), else -> FFN1 (1536).
__global__ __launch_bounds__(256, 2) void attn_ffn1(
    const u16* __restrict__ qkv, const u16* __restrict__ VTg,
    const u16* __restrict__ biasPb, u16* __restrict__ Og,
    const u16* __restrict__ hn, const u16* __restrict__ W1T,
    u16* __restrict__ Gg, const float* __restrict__ bf1f){
  __shared__ __align__(16) u16 sm[33792];   // attn: 66 KB; gemm uses first 32 KB
  const int bid = blockIdx.x;
  const int t = bid / 3, r = bid - t * 3;
  if (r == 0) attn_body(t, sm, qkv, VTg, biasPb, Og);
  else        ffn1_body(2*t + (r-1), sm, hn, W1T, Gg, bf1f);
}

// ---------------------------------------------------------------------------
// Final GEMM, concatenated K = 3840: d_out = Gg@W2T (K 0..3072)
//   + Og@WoT (K 3072..3840) + (bf2+bo) + x.  f32 out; o-proj fused.
__global__ __launch_bounds__(256, 2) void gemm_fin(
    const u16* __restrict__ Gg, const u16* __restrict__ Og,
    const u16* __restrict__ W2T, const u16* __restrict__ WoT,
    float* __restrict__ Cout, const float* __restrict__ bo2,
    const float* __restrict__ x){
  const int Nn = 768;
  __shared__ __align__(16) u16 As[128*64];
  __shared__ __align__(16) u16 Bs[128*64];
  const int tid = threadIdx.x, lane = tid & 63, wave = tid >> 6;
  const int wm = wave >> 1, wn = wave & 1;
  const int l15 = lane & 15, lg = lane >> 4;
  const int bid = blockIdx.y * gridDim.x + blockIdx.x;
  const int cpx = (gridDim.x * gridDim.y) >> 3;
  const int swz = (bid & 7) * cpx + (bid >> 3);
  const int m0 = (swz / gridDim.x) * 128, n0 = (swz % gridDim.x) * 128;
  f32x4 acc[4][4] = {};
  for (int k0 = 0; k0 < 3840; k0 += 64){
    const u16* Ab; const u16* Bb; int str; int kk0;
    if (k0 < 3072){ Ab = Gg; Bb = W2T; str = 3072; kk0 = k0; }
    else          { Ab = Og; Bb = WoT; str = 768;  kk0 = k0 - 3072; }
    #pragma unroll
    for (int i = 0; i < 4; i++){
      int chunk = i*256 + tid;
      int row = chunk >> 3, seg = (chunk & 7) ^ (row & 7);
      __builtin_amdgcn_global_load_lds(
        (const __attribute__((address_space(1))) void*)&Ab[(size_t)(m0+row)*str + kk0 + seg*8],
        (__attribute__((address_space(3))) void*)&As[(size_t)(i*256 + wave*64)*8], 16, 0, 0);
      __builtin_amdgcn_global_load_lds(
        (const __attribute__((address_space(1))) void*)&Bb[(size_t)(n0+row)*str + kk0 + seg*8],
        (__attribute__((address_space(3))) void*)&Bs[(size_t)(i*256 + wave*64)*8], 16, 0, 0);
    }
    __syncthreads();
    bf16x8 af[4][2], bfr[4][2];
    #pragma unroll
    for (int i = 0; i < 4; i++){
      int ra = wm*64 + i*16 + l15, rb = wn*64 + i*16 + l15;
      #pragma unroll
      for (int kk = 0; kk < 2; kk++){
        af[i][kk]  = *(const bf16x8*)&As[ra*64 + (((kk*4 + lg) ^ (l15 & 7)) << 3)];
        bfr[i][kk] = *(const bf16x8*)&Bs[rb*64 + (((kk*4 + lg) ^ (l15 & 7)) << 3)];
      }
    }
    #pragma unroll
    for (int kk = 0; kk < 2; kk++)
      #pragma unroll
      for (int i = 0; i < 4; i++)
        #pragma unroll
        for (int j = 0; j < 4; j++)
          acc[i][j] = __builtin_amdgcn_mfma_f32_16x16x32_bf16(af[i][kk], bfr[j][kk], acc[i][j], 0, 0, 0);
    __syncthreads();
  }
  #pragma unroll
  for (int i = 0; i < 4; i++){
    int row_base = m0 + wm*64 + i*16 + lg*4;
    #pragma unroll
    for (int j = 0; j < 4; j++){
      int col = n0 + wn*64 + j*16 + l15;
      float bcol = bo2[col];
      #pragma unroll
      for (int r = 0; r < 4; r++){
        size_t idx = (size_t)(row_base + r) * Nn + col;
        Cout[idx] = acc[i][j][r] + bcol + x[idx];
      }
    }
  }
}

// ---------------------------------------------------------------------------
extern "C" void kernel_launch(void* const* d_in, const int* in_sizes, int n_in,
                              void* d_out, int out_size, void* d_ws, size_t ws_size,
                              hipStream_t stream){
  const float* x   = (const float*)d_in[0];
  const float* sp  = (const float*)d_in[1];
  const float* ed  = (const float*)d_in[2];
  const float* Wq  = (const float*)d_in[3];
  const float* Wk  = (const float*)d_in[4];
  const float* Wv  = (const float*)d_in[5];
  const float* bv  = (const float*)d_in[6];
  const float* Wo  = (const float*)d_in[7];
  const float* bo  = (const float*)d_in[8];
  const float* g1  = (const float*)d_in[9];
  const float* be1 = (const float*)d_in[10];
  const float* g2  = (const float*)d_in[11];
  const float* be2 = (const float*)d_in[12];
  const float* W1  = (const float*)d_in[13];
  const float* bf1 = (const float*)d_in[14];
  const float* W2  = (const float*)d_in[15];
  const float* bf2 = (const float*)d_in[16];

  char* w = (char*)d_ws;
  size_t off = 0;
  auto alloc = [&](size_t bytes)->void*{ void* p = w + off; off += (bytes + 255) & ~(size_t)255; return p; };
  u16*   Gg    = (u16*)  alloc(8192ull*3072*2);   // 50.3 MB
  u16*   qkv   = (u16*)  alloc(8192ull*2304*2);   // 37.7 MB
  u16*   VTg   = (u16*)  alloc(8192ull*768*2);
  u16*   hn    = (u16*)  alloc(8192ull*768*2);
  u16*   Og    = (u16*)  alloc(8192ull*768*2);
  u16*   biasPb= (u16*)  alloc(16ull*512*512*2);
  u16*   WqkvT = (u16*)  alloc(2304ull*768*2);
  u16*   WoT   = (u16*)  alloc(768ull*768*2);
  u16*   W1T   = (u16*)  alloc(3072ull*768*2);
  u16*   W2T   = (u16*)  alloc(768ull*3072*2);
  float* qkvb  = (float*)alloc(2304ull*4);
  float* bf1f  = (float*)alloc(3072ull*4);
  float* bo2   = (float*)alloc(768ull*4);

  const float qscale = 0.03608439182435161f * LOG2E;  // D^-0.5 * log2e folded into Wq

  // --- prep: 4 independent jobs, one dispatch ---
  prep_all<<<13152, 256, 0, stream>>>(sp, ed, Wq, Wk, Wv, Wo, W1, W2, g1, g2,
                                      be1, be2, bv, bf1, bo, bf2, x,
                                      biasPb, WqkvT, WoT, W1T, W2T,
                                      qkvb, bf1f, bo2, hn, qscale);

  // --- qkv projection with fused V-transpose ---
  gemm_qkv<<<dim3(18,64),256,0,stream>>>(hn, WqkvT, qkv, qkvb, VTg);

  // --- attention + FFN1 fused (independent work, co-scheduled) ---
  attn_ffn1<<<2304, 256, 0, stream>>>(qkv, VTg, biasPb, Og, hn, W1T, Gg, bf1f);

  // --- final: FFN2 + o-proj as one concatenated-K GEMM (+bo2 +x) ---
  gemm_fin<<<dim3(6,64),256,0,stream>>>(Gg, Og, W2T, WoT, (float*)d_out, bo2, x);
}